// Round 4
// baseline (830.323 us; speedup 1.0000x reference)
//
#include <hip/hip_runtime.h>

#define PIX 4096
#define SCALE 0.25f

typedef _Float16 f16x8 __attribute__((ext_vector_type(8)));
typedef _Float16 f16x4 __attribute__((ext_vector_type(4)));
typedef float f32x4 __attribute__((ext_vector_type(4)));

__device__ inline void gload_lds16(const _Float16* g, _Float16* l) {
  __builtin_amdgcn_global_load_lds((const __attribute__((address_space(1))) void*)g,
                                   (__attribute__((address_space(3))) void*)l, 16, 0, 0);
}

// ---- elementwise fp32 -> fp16 ----
__global__ __launch_bounds__(256) void k_cvt(const float* __restrict__ in,
                                             _Float16* __restrict__ out, int n) {
  int i = blockIdx.x * 256 + threadIdx.x;
  if (i < n) out[i] = (_Float16)in[i];
}

// ---- Wbig: block-lower-triangular cascade weight (512x512), fp16 ----
__global__ __launch_bounds__(256) void k_build_wbig(const float* __restrict__ vs_w,
                                                    _Float16* __restrict__ Wbig) {
  int row = blockIdx.x;
  int i = row >> 6, d = row & 63;
  for (int col = threadIdx.x; col < 512; col += 256) {
    int j = col >> 6, c = col & 63;
    Wbig[row * 512 + col] = (j <= i) ? (_Float16)vs_w[i * 4096 + d * 64 + c] : (_Float16)0;
  }
}

// ---- x [b][512][4096] fp32 -> xh [b][4096][512] fp16 ---- grid (64,8,32)
__global__ __launch_bounds__(256) void k_xt(const float* __restrict__ x,
                                            _Float16* __restrict__ xh) {
  __shared__ float tile[64][65];
  int b = blockIdx.z, k0 = blockIdx.y * 64, p0 = blockIdx.x * 64;
  const float* xp = x + ((size_t)b * 512 + k0) * PIX + p0;
  _Float16* out = xh + (size_t)b * PIX * 512;
  int t = threadIdx.x;
  int r = t >> 4, c4 = (t & 15) << 2;
#pragma unroll
  for (int it = 0; it < 4; ++it) {
    float4 v = *(const float4*)&xp[(size_t)(r + it * 16) * PIX + c4];
    tile[r + it * 16][c4 + 0] = v.x; tile[r + it * 16][c4 + 1] = v.y;
    tile[r + it * 16][c4 + 2] = v.z; tile[r + it * 16][c4 + 3] = v.w;
  }
  __syncthreads();
  int pr = t >> 5, kk = (t & 31) << 1;
#pragma unroll
  for (int it = 0; it < 8; ++it) {
    int p = pr + it * 8;
    union { _Float16 h[2]; unsigned int u; } pk;
    pk.h[0] = (_Float16)tile[kk][p]; pk.h[1] = (_Float16)tile[kk + 1][p];
    *(unsigned int*)&out[(size_t)(p0 + p) * 512 + k0 + kk] = pk.u;
  }
}

// ---- 2-phase MFMA GEMM: C[b][m][p] = sum_k A[m][k]*B[b][p][k] + bias[m] ----
// flat grid nwg = 32 * nwg_m * 32 (nwg % 8 == 0), XCD-swizzled.
__global__ __launch_bounds__(256) void k_mgemm2(const _Float16* __restrict__ A,
                                                const _Float16* __restrict__ B,
                                                const float* __restrict__ bias,
                                                float* C, _Float16* H,
                                                int M, int tri, int out16, int nwg_m) {
  __shared__ __align__(16) _Float16 As[2][128 * 32];
  __shared__ __align__(16) _Float16 Bs[2][128 * 32];
  int nwg = gridDim.x;
  int id = blockIdx.x;
  int qq = nwg >> 3;
  id = (id & 7) * qq + (id >> 3);          // bijective XCD swizzle (nwg%8==0)
  int pb = id & 31;
  int mb = (id >> 5) % nwg_m;
  int b  = (id >> 5) / nwg_m;
  int m0 = mb * 128, p0 = pb * 128;
  const _Float16* Bb = B + (size_t)b * 2097152;
  int t = threadIdx.x, wid = t >> 6, lane = t & 63;
  int wm = (wid >> 1) * 64, wn = (wid & 1) * 64;
  int lr = lane & 15, q = lane >> 4;
  f32x4 acc[4][4] = {};
  int kend = tri ? (m0 + 128) : 512;
  int nt = kend >> 5;
  int L0 = wid * 64 + lane, r0 = L0 >> 2, c0 = (L0 & 3) ^ ((r0 >> 1) & 3);
  int L1 = (4 + wid) * 64 + lane, r1 = L1 >> 2, c1 = (L1 & 3) ^ ((r1 >> 1) & 3);
  const _Float16* Ab = A + (size_t)m0 * 512;
  const _Float16* Bp = Bb + (size_t)p0 * 512;
  size_t ga0 = (size_t)r0 * 512 + c0 * 8, ga1 = (size_t)r1 * 512 + c1 * 8;
  // prologue: stage tile 0 into buf 0
  gload_lds16(Ab + ga0, &As[0][wid * 512]);
  gload_lds16(Ab + ga1, &As[0][(4 + wid) * 512]);
  gload_lds16(Bp + ga0, &Bs[0][wid * 512]);
  gload_lds16(Bp + ga1, &Bs[0][(4 + wid) * 512]);
  __syncthreads();
  int cur = 0;
  for (int tt = 0; tt < nt; ++tt) {
    if (tt + 1 < nt) {                     // stage next tile while computing
      int k0 = (tt + 1) << 5;
      gload_lds16(Ab + ga0 + k0, &As[cur ^ 1][wid * 512]);
      gload_lds16(Ab + ga1 + k0, &As[cur ^ 1][(4 + wid) * 512]);
      gload_lds16(Bp + ga0 + k0, &Bs[cur ^ 1][wid * 512]);
      gload_lds16(Bp + ga1 + k0, &Bs[cur ^ 1][(4 + wid) * 512]);
    }
    f16x8 af[4], bf_[4];
#pragma unroll
    for (int mi = 0; mi < 4; ++mi) {
      int rr = wm + mi * 16 + lr;
      af[mi] = *(const f16x8*)&As[cur][rr * 32 + ((q ^ ((rr >> 1) & 3)) << 3)];
    }
#pragma unroll
    for (int ni = 0; ni < 4; ++ni) {
      int rr = wn + ni * 16 + lr;
      bf_[ni] = *(const f16x8*)&Bs[cur][rr * 32 + ((q ^ ((rr >> 1) & 3)) << 3)];
    }
#pragma unroll
    for (int mi = 0; mi < 4; ++mi)
#pragma unroll
      for (int ni = 0; ni < 4; ++ni)
        acc[mi][ni] = __builtin_amdgcn_mfma_f32_16x16x32_f16(af[mi], bf_[ni], acc[mi][ni], 0, 0, 0);
    __syncthreads();
    cur ^= 1;
  }
#pragma unroll
  for (int mi = 0; mi < 4; ++mi) {
#pragma unroll
    for (int rr = 0; rr < 4; ++rr) {
      int m = m0 + wm + mi * 16 + q * 4 + rr;
      float bi = bias[m];
      size_t base = ((size_t)b * M + m) * PIX + p0 + wn;
      if (out16) {
        _Float16* crow = H + base;
#pragma unroll
        for (int ni = 0; ni < 4; ++ni)
          crow[ni * 16 + lr] = (_Float16)(acc[mi][ni][rr] + bi);
      } else {
        float* crow = C + base;
#pragma unroll
        for (int ni = 0; ni < 4; ++ni)
          crow[ni * 16 + lr] = acc[mi][ni][rr] + bi;
      }
    }
  }
}

// ---- depthwise 5x5 SAME conv on q-half of feat ---- grid (128, B)
__global__ __launch_bounds__(256) void k_dwconv(const float* __restrict__ feat,
                                                const float* __restrict__ w,
                                                const float* __restrict__ bias,
                                                float* __restrict__ qconv) {
  __shared__ float tile[68][68];
  int c = blockIdx.x, b = blockIdx.y;
  const float* in = feat + ((size_t)b * 256 + c) * PIX;
  float wreg[25];
#pragma unroll
  for (int i = 0; i < 25; ++i) wreg[i] = w[c * 25 + i];
  float bi = bias[c];
  int t = threadIdx.x;
  for (int idx = t; idx < 68 * 68; idx += 256) {
    int y = idx / 68, xx = idx - y * 68;
    int h = y - 2, ww = xx - 2;
    float v = 0.f;
    if (h >= 0 && h < 64 && ww >= 0 && ww < 64) v = in[h * 64 + ww];
    tile[y][xx] = v;
  }
  __syncthreads();
  float* out = qconv + ((size_t)b * 128 + c) * PIX;
  int tx = (t & 15) << 2, ty = (t >> 4) << 2;
#pragma unroll
  for (int i = 0; i < 4; ++i) {
    float4 o;
    float* po = (float*)&o;
#pragma unroll
    for (int j = 0; j < 4; ++j) {
      float s = bi;
#pragma unroll
      for (int dy = 0; dy < 5; ++dy)
#pragma unroll
        for (int dx = 0; dx < 5; ++dx)
          s += wreg[dy * 5 + dx] * tile[ty + i + dy][tx + j + dx];
      po[j] = s;
    }
    *(float4*)&out[(ty + i) * 64 + tx] = o;
  }
}

// ---- fp32 [128c][4096p] (offset ic0, b-stride ibs) -> fp16 [4096p][128c] ----
// grid (64, 32)
__global__ __launch_bounds__(256) void k_qkt(const float* __restrict__ in, long ibs, int ic0,
                                             _Float16* __restrict__ out) {
  __shared__ __align__(16) _Float16 Ts[64 * 136];
  int p0 = blockIdx.x * 64, b = blockIdx.y;
  const float* ip = in + (size_t)b * ibs + (size_t)ic0 * PIX;
  int t = threadIdx.x;
#pragma unroll
  for (int it = 0; it < 8; ++it) {
    int i4 = it * 256 + t;               // 2048 float4 chunks = 128c * 16
    int c = i4 >> 4, pp = (i4 & 15) << 2;
    float4 v = *(const float4*)&ip[(size_t)c * PIX + p0 + pp];
    Ts[(pp + 0) * 136 + c] = (_Float16)v.x;
    Ts[(pp + 1) * 136 + c] = (_Float16)v.y;
    Ts[(pp + 2) * 136 + c] = (_Float16)v.z;
    Ts[(pp + 3) * 136 + c] = (_Float16)v.w;
  }
  __syncthreads();
  _Float16* op = out + (size_t)b * (PIX * 128) + (size_t)p0 * 128;
#pragma unroll
  for (int it = 0; it < 4; ++it) {
    int ch = it * 256 + t;               // 1024 chunks of 8 halves
    int p = ch >> 4, cc = (ch & 15) << 3;
    *(f16x8*)&op[p * 128 + cc] = *(const f16x8*)&Ts[p * 136 + cc];
  }
}

// ---- MFMA attention scores+softmax -> fp16 attn [b][j][q][k] ----
// grid (64 j, 32 b, 2 which). which=0: slab h=j (rows p=j*64+r), bias_w.
//                             which=1: slab w=j (rows p=j+64r), bias_h.
__global__ __launch_bounds__(256) void k_mattn(const _Float16* __restrict__ qh,
                                               const _Float16* __restrict__ kh,
                                               const float* __restrict__ bias_w,
                                               const float* __restrict__ bias_h,
                                               _Float16* __restrict__ attnW,
                                               _Float16* __restrict__ attnH) {
  __shared__ __align__(16) _Float16 Qs[64 * 136];
  __shared__ __align__(16) _Float16 Ks[64 * 136];
  __shared__ float bl[64];
  int j = blockIdx.x, b = blockIdx.y, which = blockIdx.z;
  const float* bias = which ? bias_h : bias_w;
  _Float16* attn = which ? attnH : attnW;
  int t = threadIdx.x;
  if (t < 64) bl[t] = bias[t];
  const _Float16* qb = qh + (size_t)b * (PIX * 128);
  const _Float16* kb = kh + (size_t)b * (PIX * 128);
#pragma unroll
  for (int it = 0; it < 4; ++it) {
    int idx = it * 256 + t;              // 1024 chunks: 64 rows * 16
    int r = idx >> 4, cc = (idx & 15) << 3;
    size_t p = which ? (size_t)(j + 64 * r) : (size_t)(j * 64 + r);
    *(f16x8*)&Qs[r * 136 + cc] = *(const f16x8*)&qb[p * 128 + cc];
    *(f16x8*)&Ks[r * 136 + cc] = *(const f16x8*)&kb[p * 128 + cc];
  }
  __syncthreads();
  int wave = t >> 6, lane = t & 63;
  int lr = lane & 15, q4 = lane >> 4;
  f16x8 af[4];
#pragma unroll
  for (int kk = 0; kk < 4; ++kk)
    af[kk] = *(const f16x8*)&Qs[(wave * 16 + lr) * 136 + q4 * 8 + kk * 32];
  f32x4 acc[4] = {};
#pragma unroll
  for (int ni = 0; ni < 4; ++ni)
#pragma unroll
    for (int kk = 0; kk < 4; ++kk) {
      f16x8 bf = *(const f16x8*)&Ks[(ni * 16 + lr) * 136 + q4 * 8 + kk * 32];
      acc[ni] = __builtin_amdgcn_mfma_f32_16x16x32_f16(af[kk], bf, acc[ni], 0, 0, 0);
    }
  // softmax: row q = wave*16 + q4*4 + r lives across lr lanes (cols k = ni*16+lr)
  float ev[4][4], mx[4], sm[4];
#pragma unroll
  for (int r = 0; r < 4; ++r) {
    int qrow = wave * 16 + q4 * 4 + r;
    float m = -1e30f;
#pragma unroll
    for (int ni = 0; ni < 4; ++ni) {
      int k = ni * 16 + lr;
      ev[ni][r] = acc[ni][r] * SCALE + bl[abs(qrow - k)];
      m = fmaxf(m, ev[ni][r]);
    }
    m = fmaxf(m, __shfl_xor(m, 1)); m = fmaxf(m, __shfl_xor(m, 2));
    m = fmaxf(m, __shfl_xor(m, 4)); m = fmaxf(m, __shfl_xor(m, 8));
    mx[r] = m;
    float s = 0.f;
#pragma unroll
    for (int ni = 0; ni < 4; ++ni) { ev[ni][r] = __expf(ev[ni][r] - m); s += ev[ni][r]; }
    s += __shfl_xor(s, 1); s += __shfl_xor(s, 2);
    s += __shfl_xor(s, 4); s += __shfl_xor(s, 8);
    sm[r] = 1.f / s;
  }
  _Float16* ab = attn + (((size_t)b * 64 + j) * 64) * 64;
#pragma unroll
  for (int r = 0; r < 4; ++r) {
    int qrow = wave * 16 + q4 * 4 + r;
#pragma unroll
    for (int ni = 0; ni < 4; ++ni)
      ab[qrow * 64 + ni * 16 + lr] = (_Float16)(ev[ni][r] * sm[r]);
  }
}

// ---- F1: w-mix + transpose. tT[b][ch][w*64+h] = sum_k attnW[b][h][w][k]*Vh[b][ch][h*64+k]
// grid (64 chb(8ch), 32 b)
__global__ __launch_bounds__(256) void k_f1(const _Float16* __restrict__ Vh,
                                            const _Float16* __restrict__ attnW,
                                            _Float16* __restrict__ tT) {
  __shared__ __align__(16) _Float16 Vt[8 * 4104];        // [ch8][p4096 pad]
  __shared__ __align__(16) _Float16 T2[8 * 64 * 68];     // [ch8][w64][h64 pad68]
  int chb = blockIdx.x, b = blockIdx.y;
  int t = threadIdx.x, wid = t >> 6, lane = t & 63;
  int lr = lane & 15, q4 = lane >> 4;
  const _Float16* Vb = Vh + ((size_t)b * 512 + chb * 8) * PIX;
#pragma unroll
  for (int it = 0; it < 16; ++it) {
    int idx = it * 256 + t;              // 4096 chunks of 8 halves
    int cc = idx >> 9, off = (idx & 511) << 3;
    *(f16x8*)&Vt[cc * 4104 + off] = *(const f16x8*)&Vb[(size_t)cc * PIX + off];
  }
  __syncthreads();
  const _Float16* Aw = attnW + (size_t)(b * 64) * 4096;
  for (int hh = 0; hh < 16; ++hh) {
    int h = wid * 16 + hh;
    f16x8 af[2] = {};
    if (lr < 8) {
#pragma unroll
      for (int kk = 0; kk < 2; ++kk)
        af[kk] = *(const f16x8*)&Vt[lr * 4104 + h * 64 + q4 * 8 + kk * 32];
    }
    const _Float16* Ah = Aw + (size_t)h * 4096;
    f32x4 acc[4] = {};
#pragma unroll
    for (int ni = 0; ni < 4; ++ni)
#pragma unroll
      for (int kk = 0; kk < 2; ++kk) {
        f16x8 bf = *(const f16x8*)&Ah[(ni * 16 + lr) * 64 + q4 * 8 + kk * 32];
        acc[ni] = __builtin_amdgcn_mfma_f32_16x16x32_f16(af[kk], bf, acc[ni], 0, 0, 0);
      }
    // C rows = ch (q4*4+r, valid q4<2), cols w' = ni*16+lr
    if (q4 < 2) {
#pragma unroll
      for (int ni = 0; ni < 4; ++ni)
#pragma unroll
        for (int r = 0; r < 4; ++r)
          T2[(q4 * 4 + r) * 4352 + (ni * 16 + lr) * 68 + h] = (_Float16)acc[ni][r];
    }
  }
  __syncthreads();
  _Float16* tb = tT + ((size_t)b * 512 + chb * 8) * PIX;
#pragma unroll
  for (int it = 0; it < 32; ++it) {
    int idx = it * 256 + t;              // 8192 chunks of 4 halves
    int cc = idx >> 10, rem = idx & 1023;
    int w = rem >> 4, hc = (rem & 15) << 2;
    *(f16x4*)&tb[(size_t)cc * PIX + w * 64 + hc] = *(const f16x4*)&T2[cc * 4352 + w * 68 + hc];
  }
}

// ---- F2: h-mix + relu + ght. ght[b][h*64+w][ch] = relu(sum_k attnH[b][w][h][k]*tT[b][ch][w*64+k])
// grid (64 w, 32 b); ch in 8 blocks of 64
__global__ __launch_bounds__(256) void k_f2(const _Float16* __restrict__ tT,
                                            const _Float16* __restrict__ attnH,
                                            _Float16* __restrict__ ght) {
  __shared__ __align__(16) _Float16 Ts[64 * 72];   // [ch64][h64 pad72]
  __shared__ __align__(16) _Float16 Ls[64 * 72];   // [h'64][ch64 pad72]
  int w = blockIdx.x, b = blockIdx.y;
  int t = threadIdx.x, wid = t >> 6, lane = t & 63;
  int lr = lane & 15, q4 = lane >> 4;
  const _Float16* Ab = attnH + ((size_t)b * 64 + w) * 4096;
  f16x8 af[2];
#pragma unroll
  for (int kk = 0; kk < 2; ++kk)
    af[kk] = *(const f16x8*)&Ab[(wid * 16 + lr) * 64 + q4 * 8 + kk * 32];
  const _Float16* tb = tT + (size_t)b * 512 * PIX + w * 64;
  _Float16* gb = ght + ((size_t)b * PIX + w) * 512;
  for (int cb = 0; cb < 8; ++cb) {
#pragma unroll
    for (int it = 0; it < 2; ++it) {
      int idx = it * 256 + t;            // 512 chunks of 8: 64ch x 8
      int cc = idx >> 3, hc = (idx & 7) << 3;
      *(f16x8*)&Ts[cc * 72 + hc] = *(const f16x8*)&tb[(size_t)(cb * 64 + cc) * PIX + hc];
    }
    __syncthreads();
    f32x4 acc[4] = {};
#pragma unroll
    for (int ni = 0; ni < 4; ++ni)
#pragma unroll
      for (int kk = 0; kk < 2; ++kk) {
        f16x8 bf = *(const f16x8*)&Ts[(ni * 16 + lr) * 72 + q4 * 8 + kk * 32];
        acc[ni] = __builtin_amdgcn_mfma_f32_16x16x32_f16(af[kk], bf, acc[ni], 0, 0, 0);
      }
    // C rows h' = wid*16+q4*4+r, cols ch = ni*16+lr ; relu -> Ls[h'][ch]
#pragma unroll
    for (int ni = 0; ni < 4; ++ni)
#pragma unroll
      for (int r = 0; r < 4; ++r) {
        float v = acc[ni][r];
        Ls[(wid * 16 + q4 * 4 + r) * 72 + ni * 16 + lr] = (_Float16)(v > 0.f ? v : 0.f);
      }
    __syncthreads();
#pragma unroll
    for (int it = 0; it < 2; ++it) {
      int idx = it * 256 + t;            // 512 chunks of 8: 64h' x 8
      int hp = idx >> 3, cc = (idx & 7) << 3;
      *(f16x8*)&gb[(size_t)hp * 32768 + cb * 64 + cc] = *(const f16x8*)&Ls[hp * 72 + cc];
    }
  }
}

extern "C" void kernel_launch(void* const* d_in, const int* in_sizes, int n_in,
                              void* d_out, int out_size, void* d_ws, size_t ws_size,
                              hipStream_t stream) {
  const float* x      = (const float*)d_in[0];
  const float* qk_w   = (const float*)d_in[1];
  const float* qk_b   = (const float*)d_in[2];
  const float* dws_w  = (const float*)d_in[3];
  const float* dws_b  = (const float*)d_in[4];
  const float* vs_w   = (const float*)d_in[5];
  const float* vs_b   = (const float*)d_in[6];
  const float* proj_w = (const float*)d_in[7];
  const float* proj_b = (const float*)d_in[8];
  const float* bias_h = (const float*)d_in[9];
  const float* bias_w = (const float*)d_in[10];

  float* ws = (float*)d_ws;
  float* dout = (float*)d_out;

  // ws layout (float units), ~303 MB total:
  _Float16* xh    = (_Float16*)ws;                 // [0,33.5M fl) x^T fp16; reused as ght
  _Float16* ght   = xh;
  float*    feat  = ws + 33554432;                 // [33.5M,67.1M fl) fp32; reused as tT
  _Float16* tT    = (_Float16*)(ws + 33554432);
  _Float16* attnW = (_Float16*)(ws + 67108864);    // 8.4M halves
  _Float16* attnH = (_Float16*)(ws + 71303168);    // 8.4M halves
  _Float16* qkw_h  = (_Float16*)(ws + 75497472);   // 131072 halves
  _Float16* wbig_h = (_Float16*)(ws + 75563008);   // 262144 halves
  _Float16* pjw_h  = (_Float16*)(ws + 75694080);   // 262144 halves -> end 75,825,152 fl

  // d_out phase scratch:
  float*    qconv = dout;                          // [0,16.8M fl)
  _Float16* qh    = (_Float16*)(dout + 16777216);  // 16.8M halves
  _Float16* kh    = (_Float16*)(dout + 25165824);  // 16.8M halves
  _Float16* Vh    = (_Float16*)(dout + 33554432);  // 67.1M halves

  k_cvt<<<dim3(512), 256, 0, stream>>>(qk_w, qkw_h, 131072);
  k_cvt<<<dim3(1024), 256, 0, stream>>>(proj_w, pjw_h, 262144);
  k_build_wbig<<<512, 256, 0, stream>>>(vs_w, wbig_h);
  k_xt<<<dim3(64, 8, 32), 256, 0, stream>>>(x, xh);
  // feat = qk_w @ x + qk_b (fp32)
  k_mgemm2<<<2048, 256, 0, stream>>>(qkw_h, xh, qk_b, feat, nullptr, 256, 0, 0, 2);
  k_dwconv<<<dim3(128, 32), 256, 0, stream>>>(feat, dws_w, dws_b, qconv);
  // qh/kh = [p][c] fp16 transposes of qconv / feat k-half
  k_qkt<<<dim3(64, 32), 256, 0, stream>>>(qconv, 128L * PIX, 0, qh);
  k_qkt<<<dim3(64, 32), 256, 0, stream>>>(feat, 256L * PIX, 128, kh);
  // both attention maps (fp16)
  k_mattn<<<dim3(64, 32, 2), 256, 0, stream>>>(qh, kh, bias_w, bias_h, attnW, attnH);
  // V = Wbig @ x + vs_b (triangular, fp16)
  k_mgemm2<<<4096, 256, 0, stream>>>(wbig_h, xh, vs_b, nullptr, Vh, 512, 1, 1, 4);
  // t^T = w-mix(V) transposed
  k_f1<<<dim3(64, 32), 256, 0, stream>>>(Vh, attnW, tT);
  // ght = relu(h-mix(tT)) in [p][ch]
  k_f2<<<dim3(64, 32), 256, 0, stream>>>(tT, attnH, ght);
  // out = proj_w @ g + proj_b (fp32)
  k_mgemm2<<<4096, 256, 0, stream>>>(pjw_h, ght, proj_b, dout, nullptr, 512, 0, 0, 4);
}

// Round 5
// 758.639 us; speedup vs baseline: 1.0945x; 1.0945x over previous
//
#include <hip/hip_runtime.h>

#define PIX 4096
#define SCALE 0.25f

typedef _Float16 f16x8 __attribute__((ext_vector_type(8)));
typedef float f32x4 __attribute__((ext_vector_type(4)));

__device__ inline void gload_lds16(const _Float16* g, _Float16* l) {
  __builtin_amdgcn_global_load_lds((const __attribute__((address_space(1))) void*)g,
                                   (__attribute__((address_space(3))) void*)l, 16, 0, 0);
}

// ---- elementwise fp32 -> fp16 ----
__global__ __launch_bounds__(256) void k_cvt(const float* __restrict__ in,
                                             _Float16* __restrict__ out, int n) {
  int i = blockIdx.x * 256 + threadIdx.x;
  if (i < n) out[i] = (_Float16)in[i];
}

// ---- Wbig: block-lower-triangular cascade weight (512x512), fp16 ----
__global__ __launch_bounds__(256) void k_build_wbig(const float* __restrict__ vs_w,
                                                    _Float16* __restrict__ Wbig) {
  int row = blockIdx.x;
  int i = row >> 6, d = row & 63;
  for (int col = threadIdx.x; col < 512; col += 256) {
    int j = col >> 6, c = col & 63;
    Wbig[row * 512 + col] = (j <= i) ? (_Float16)vs_w[i * 4096 + d * 64 + c] : (_Float16)0;
  }
}

// ---- x [b][512][4096] fp32 -> xh [b][4096][512] fp16 ---- grid (64,8,32)
__global__ __launch_bounds__(256) void k_xt(const float* __restrict__ x,
                                            _Float16* __restrict__ xh) {
  __shared__ float tile[64][65];
  int b = blockIdx.z, k0 = blockIdx.y * 64, p0 = blockIdx.x * 64;
  const float* xp = x + ((size_t)b * 512 + k0) * PIX + p0;
  _Float16* out = xh + (size_t)b * PIX * 512;
  int t = threadIdx.x;
  int r = t >> 4, c4 = (t & 15) << 2;
#pragma unroll
  for (int it = 0; it < 4; ++it) {
    float4 v = *(const float4*)&xp[(size_t)(r + it * 16) * PIX + c4];
    tile[r + it * 16][c4 + 0] = v.x; tile[r + it * 16][c4 + 1] = v.y;
    tile[r + it * 16][c4 + 2] = v.z; tile[r + it * 16][c4 + 3] = v.w;
  }
  __syncthreads();
  int pr = t >> 5, kk = (t & 31) << 1;
#pragma unroll
  for (int it = 0; it < 8; ++it) {
    int p = pr + it * 8;
    union { _Float16 h[2]; unsigned int u; } pk;
    pk.h[0] = (_Float16)tile[kk][p]; pk.h[1] = (_Float16)tile[kk + 1][p];
    *(unsigned int*)&out[(size_t)(p0 + p) * 512 + k0 + kk] = pk.u;
  }
}

// ---- 2-phase MFMA GEMM: C[b][m][p] = sum_k A[m][k]*B[b][p][k] + bias[m] ----
// flat grid nwg = 32 * nwg_m * 32 (nwg % 8 == 0), XCD-swizzled, mb fastest (B-panel L2 reuse).
__global__ __launch_bounds__(256) void k_mgemm2(const _Float16* __restrict__ A,
                                                const _Float16* __restrict__ B,
                                                const float* __restrict__ bias,
                                                float* C, _Float16* H,
                                                int M, int tri, int out16, int nwg_m) {
  __shared__ __align__(16) _Float16 As[2][128 * 32];
  __shared__ __align__(16) _Float16 Bs[2][128 * 32];
  int nwg = gridDim.x;
  int id = blockIdx.x;
  int qq = nwg >> 3;
  id = (id & 7) * qq + (id >> 3);          // bijective XCD swizzle (nwg%8==0)
  int mb = id % nwg_m;
  int rest = id / nwg_m;
  int pb = rest & 31;
  int b  = rest >> 5;
  int m0 = mb * 128, p0 = pb * 128;
  const _Float16* Bb = B + (size_t)b * 2097152;
  int t = threadIdx.x, wid = t >> 6, lane = t & 63;
  int wm = (wid >> 1) * 64, wn = (wid & 1) * 64;
  int lr = lane & 15, q = lane >> 4;
  f32x4 acc[4][4] = {};
  int kend = tri ? (m0 + 128) : 512;
  int nt = kend >> 5;
  int L0 = wid * 64 + lane, r0 = L0 >> 2, c0 = (L0 & 3) ^ ((r0 >> 1) & 3);
  int L1 = (4 + wid) * 64 + lane, r1 = L1 >> 2, c1 = (L1 & 3) ^ ((r1 >> 1) & 3);
  const _Float16* Ab = A + (size_t)m0 * 512;
  const _Float16* Bp = Bb + (size_t)p0 * 512;
  size_t ga0 = (size_t)r0 * 512 + c0 * 8, ga1 = (size_t)r1 * 512 + c1 * 8;
  gload_lds16(Ab + ga0, &As[0][wid * 512]);
  gload_lds16(Ab + ga1, &As[0][(4 + wid) * 512]);
  gload_lds16(Bp + ga0, &Bs[0][wid * 512]);
  gload_lds16(Bp + ga1, &Bs[0][(4 + wid) * 512]);
  __syncthreads();
  int cur = 0;
  for (int tt = 0; tt < nt; ++tt) {
    if (tt + 1 < nt) {
      int k0 = (tt + 1) << 5;
      gload_lds16(Ab + ga0 + k0, &As[cur ^ 1][wid * 512]);
      gload_lds16(Ab + ga1 + k0, &As[cur ^ 1][(4 + wid) * 512]);
      gload_lds16(Bp + ga0 + k0, &Bs[cur ^ 1][wid * 512]);
      gload_lds16(Bp + ga1 + k0, &Bs[cur ^ 1][(4 + wid) * 512]);
    }
    f16x8 af[4], bf_[4];
#pragma unroll
    for (int mi = 0; mi < 4; ++mi) {
      int rr = wm + mi * 16 + lr;
      af[mi] = *(const f16x8*)&As[cur][rr * 32 + ((q ^ ((rr >> 1) & 3)) << 3)];
    }
#pragma unroll
    for (int ni = 0; ni < 4; ++ni) {
      int rr = wn + ni * 16 + lr;
      bf_[ni] = *(const f16x8*)&Bs[cur][rr * 32 + ((q ^ ((rr >> 1) & 3)) << 3)];
    }
#pragma unroll
    for (int mi = 0; mi < 4; ++mi)
#pragma unroll
      for (int ni = 0; ni < 4; ++ni)
        acc[mi][ni] = __builtin_amdgcn_mfma_f32_16x16x32_f16(af[mi], bf_[ni], acc[mi][ni], 0, 0, 0);
    __syncthreads();
    cur ^= 1;
  }
#pragma unroll
  for (int mi = 0; mi < 4; ++mi) {
#pragma unroll
    for (int rr = 0; rr < 4; ++rr) {
      int m = m0 + wm + mi * 16 + q * 4 + rr;
      float bi = bias[m];
      size_t base = ((size_t)b * M + m) * PIX + p0 + wn;
      if (out16) {
        _Float16* crow = H + base;
#pragma unroll
        for (int ni = 0; ni < 4; ++ni)
          crow[ni * 16 + lr] = (_Float16)(acc[mi][ni][rr] + bi);
      } else {
        float* crow = C + base;
#pragma unroll
        for (int ni = 0; ni < 4; ++ni)
          crow[ni * 16 + lr] = acc[mi][ni][rr] + bi;
      }
    }
  }
}

// ---- depthwise 5x5 SAME conv on q-half of feat ---- grid (128, B)
__global__ __launch_bounds__(256) void k_dwconv(const float* __restrict__ feat,
                                                const float* __restrict__ w,
                                                const float* __restrict__ bias,
                                                float* __restrict__ qconv) {
  __shared__ float tile[68][68];
  int c = blockIdx.x, b = blockIdx.y;
  const float* in = feat + ((size_t)b * 256 + c) * PIX;
  float wreg[25];
#pragma unroll
  for (int i = 0; i < 25; ++i) wreg[i] = w[c * 25 + i];
  float bi = bias[c];
  int t = threadIdx.x;
  for (int idx = t; idx < 68 * 68; idx += 256) {
    int y = idx / 68, xx = idx - y * 68;
    int h = y - 2, ww = xx - 2;
    float v = 0.f;
    if (h >= 0 && h < 64 && ww >= 0 && ww < 64) v = in[h * 64 + ww];
    tile[y][xx] = v;
  }
  __syncthreads();
  float* out = qconv + ((size_t)b * 128 + c) * PIX;
  int tx = (t & 15) << 2, ty = (t >> 4) << 2;
#pragma unroll
  for (int i = 0; i < 4; ++i) {
    float4 o;
    float* po = (float*)&o;
#pragma unroll
    for (int j = 0; j < 4; ++j) {
      float s = bi;
#pragma unroll
      for (int dy = 0; dy < 5; ++dy)
#pragma unroll
        for (int dx = 0; dx < 5; ++dx)
          s += wreg[dy * 5 + dx] * tile[ty + i + dy][tx + j + dx];
      po[j] = s;
    }
    *(float4*)&out[(ty + i) * 64 + tx] = o;
  }
}

// ---- fp32 [128c][4096p] (offset ic0, b-stride ibs) -> fp16 [4096p][128c] ---- grid (64,32)
__global__ __launch_bounds__(256) void k_qkt(const float* __restrict__ in, long ibs, int ic0,
                                             _Float16* __restrict__ out) {
  __shared__ __align__(16) _Float16 Ts[64 * 136];
  int p0 = blockIdx.x * 64, b = blockIdx.y;
  const float* ip = in + (size_t)b * ibs + (size_t)ic0 * PIX;
  int t = threadIdx.x;
#pragma unroll
  for (int it = 0; it < 8; ++it) {
    int i4 = it * 256 + t;
    int c = i4 >> 4, pp = (i4 & 15) << 2;
    float4 v = *(const float4*)&ip[(size_t)c * PIX + p0 + pp];
    Ts[(pp + 0) * 136 + c] = (_Float16)v.x;
    Ts[(pp + 1) * 136 + c] = (_Float16)v.y;
    Ts[(pp + 2) * 136 + c] = (_Float16)v.z;
    Ts[(pp + 3) * 136 + c] = (_Float16)v.w;
  }
  __syncthreads();
  _Float16* op = out + (size_t)b * (PIX * 128) + (size_t)p0 * 128;
#pragma unroll
  for (int it = 0; it < 4; ++it) {
    int ch = it * 256 + t;
    int p = ch >> 4, cc = (ch & 15) << 3;
    *(f16x8*)&op[p * 128 + cc] = *(const f16x8*)&Ts[p * 136 + cc];
  }
}

// ---- MFMA attention scores+softmax -> fp16 attn [b][j][q][k] ---- grid (64,32,2)
__global__ __launch_bounds__(256) void k_mattn(const _Float16* __restrict__ qh,
                                               const _Float16* __restrict__ kh,
                                               const float* __restrict__ bias_w,
                                               const float* __restrict__ bias_h,
                                               _Float16* __restrict__ attnW,
                                               _Float16* __restrict__ attnH) {
  __shared__ __align__(16) _Float16 Qs[64 * 136];
  __shared__ __align__(16) _Float16 Ks[64 * 136];
  __shared__ float bl[64];
  int j = blockIdx.x, b = blockIdx.y, which = blockIdx.z;
  const float* bias = which ? bias_h : bias_w;
  _Float16* attn = which ? attnH : attnW;
  int t = threadIdx.x;
  if (t < 64) bl[t] = bias[t];
  const _Float16* qb = qh + (size_t)b * (PIX * 128);
  const _Float16* kb = kh + (size_t)b * (PIX * 128);
#pragma unroll
  for (int it = 0; it < 4; ++it) {
    int idx = it * 256 + t;
    int r = idx >> 4, cc = (idx & 15) << 3;
    size_t p = which ? (size_t)(j + 64 * r) : (size_t)(j * 64 + r);
    *(f16x8*)&Qs[r * 136 + cc] = *(const f16x8*)&qb[p * 128 + cc];
    *(f16x8*)&Ks[r * 136 + cc] = *(const f16x8*)&kb[p * 128 + cc];
  }
  __syncthreads();
  int wave = t >> 6, lane = t & 63;
  int lr = lane & 15, q4 = lane >> 4;
  f16x8 af[4];
#pragma unroll
  for (int kk = 0; kk < 4; ++kk)
    af[kk] = *(const f16x8*)&Qs[(wave * 16 + lr) * 136 + q4 * 8 + kk * 32];
  f32x4 acc[4] = {};
#pragma unroll
  for (int ni = 0; ni < 4; ++ni)
#pragma unroll
    for (int kk = 0; kk < 4; ++kk) {
      f16x8 bf = *(const f16x8*)&Ks[(ni * 16 + lr) * 136 + q4 * 8 + kk * 32];
      acc[ni] = __builtin_amdgcn_mfma_f32_16x16x32_f16(af[kk], bf, acc[ni], 0, 0, 0);
    }
  float ev[4][4], sm[4];
#pragma unroll
  for (int r = 0; r < 4; ++r) {
    int qrow = wave * 16 + q4 * 4 + r;
    float m = -1e30f;
#pragma unroll
    for (int ni = 0; ni < 4; ++ni) {
      int k = ni * 16 + lr;
      ev[ni][r] = acc[ni][r] * SCALE + bl[abs(qrow - k)];
      m = fmaxf(m, ev[ni][r]);
    }
    m = fmaxf(m, __shfl_xor(m, 1)); m = fmaxf(m, __shfl_xor(m, 2));
    m = fmaxf(m, __shfl_xor(m, 4)); m = fmaxf(m, __shfl_xor(m, 8));
    float s = 0.f;
#pragma unroll
    for (int ni = 0; ni < 4; ++ni) { ev[ni][r] = __expf(ev[ni][r] - m); s += ev[ni][r]; }
    s += __shfl_xor(s, 1); s += __shfl_xor(s, 2);
    s += __shfl_xor(s, 4); s += __shfl_xor(s, 8);
    sm[r] = 1.f / s;
  }
  _Float16* ab = attn + (((size_t)b * 64 + j) * 64) * 64;
#pragma unroll
  for (int r = 0; r < 4; ++r) {
    int qrow = wave * 16 + q4 * 4 + r;
#pragma unroll
    for (int ni = 0; ni < 4; ++ni)
      ab[qrow * 64 + ni * 16 + lr] = (_Float16)(ev[ni][r] * sm[r]);
  }
}

// ---- slab-batched attention mix, IN-PLACE on D (fp16) ----
// grid flat 8192: ct=id&3 (128ch tile), s=(id>>2)&63 (slab), b=id>>8.
// D[b][ch][s*64+q] = sum_k attn[b,s][q,k] * D[b][ch][s*64+k]
__global__ __launch_bounds__(256) void k_smix(_Float16* D, const _Float16* __restrict__ attn) {
  __shared__ __align__(16) _Float16 Vs[128 * 64];
  __shared__ __align__(16) _Float16 Ls[128 * 72];
  int id = blockIdx.x;
  int ct = id & 3, s = (id >> 2) & 63, b = id >> 8;
  int t = threadIdx.x, wid = t >> 6, lane = t & 63;
  int lr = lane & 15, q4 = lane >> 4;
  _Float16* Db = D + ((size_t)b * 512 + ct * 128) * PIX + s * 64;
  // stage 128x64 slab tile into LDS, XOR-swizzled (chunk ^= row&7)
#pragma unroll
  for (int it = 0; it < 4; ++it) {
    int idx = it * 256 + t;
    int row = idx >> 3, c = idx & 7;
    int sc = c ^ (row & 7);
    gload_lds16(Db + (size_t)row * PIX + sc * 8, &Vs[(it * 256 + wid * 64) * 8]);
  }
  // attn fragments (B-operand rows q) straight from global into regs
  const _Float16* Ab = attn + ((size_t)b * 64 + s) * 4096;
  f16x8 bfr[4][2];
#pragma unroll
  for (int ni = 0; ni < 4; ++ni)
#pragma unroll
    for (int kk = 0; kk < 2; ++kk)
      bfr[ni][kk] = *(const f16x8*)&Ab[(ni * 16 + lr) * 64 + q4 * 8 + kk * 32];
  __syncthreads();
  f32x4 acc[2][4] = {};
#pragma unroll
  for (int mi = 0; mi < 2; ++mi) {
    int rr = wid * 32 + mi * 16 + lr;
#pragma unroll
    for (int kk = 0; kk < 2; ++kk) {
      f16x8 af = *(const f16x8*)&Vs[rr * 64 + (((q4 + 4 * kk) ^ (rr & 7)) << 3)];
#pragma unroll
      for (int ni = 0; ni < 4; ++ni)
        acc[mi][ni] = __builtin_amdgcn_mfma_f32_16x16x32_f16(af, bfr[ni][kk], acc[mi][ni], 0, 0, 0);
    }
  }
  // restage output through LDS for coalesced writes
#pragma unroll
  for (int mi = 0; mi < 2; ++mi)
#pragma unroll
    for (int ni = 0; ni < 4; ++ni)
#pragma unroll
      for (int rr = 0; rr < 4; ++rr)
        Ls[(wid * 32 + mi * 16 + q4 * 4 + rr) * 72 + ni * 16 + lr] = (_Float16)acc[mi][ni][rr];
  __syncthreads();
#pragma unroll
  for (int it = 0; it < 4; ++it) {
    int idx = it * 256 + t;
    int row = idx >> 3, c = idx & 7;
    *(f16x8*)&Db[(size_t)row * PIX + c * 8] = *(const f16x8*)&Ls[row * 72 + c * 8];
  }
}

// ---- h-mix + relu + transposed write to ght ----
// grid flat 8192: ct=id&3, w=(id>>2)&63, b=id>>8.
// ght[b][h'*64+w][ct*128+chl] = relu(sum_h attnH[b,w][h',h] * tT[b][ch][w*64+h])
__global__ __launch_bounds__(256) void k_hmix(const _Float16* __restrict__ tT,
                                              const _Float16* __restrict__ attnH,
                                              _Float16* __restrict__ ght) {
  __shared__ __align__(16) _Float16 Ts[128 * 64];
  __shared__ __align__(16) _Float16 Ls[64 * 136];
  int id = blockIdx.x;
  int ct = id & 3, w = (id >> 2) & 63, b = id >> 8;
  int t = threadIdx.x, wid = t >> 6, lane = t & 63;
  int lr = lane & 15, q4 = lane >> 4;
  const _Float16* Tb = tT + ((size_t)b * 512 + ct * 128) * PIX + w * 64;
#pragma unroll
  for (int it = 0; it < 4; ++it) {
    int idx = it * 256 + t;
    int row = idx >> 3, c = idx & 7;
    int sc = c ^ (row & 7);
    gload_lds16(Tb + (size_t)row * PIX + sc * 8, &Ts[(it * 256 + wid * 64) * 8]);
  }
  const _Float16* Ab = attnH + ((size_t)b * 64 + w) * 4096;
  f16x8 bfr[4][2];
#pragma unroll
  for (int ni = 0; ni < 4; ++ni)
#pragma unroll
    for (int kk = 0; kk < 2; ++kk)
      bfr[ni][kk] = *(const f16x8*)&Ab[(ni * 16 + lr) * 64 + q4 * 8 + kk * 32];
  __syncthreads();
  f32x4 acc[2][4] = {};
#pragma unroll
  for (int mi = 0; mi < 2; ++mi) {
    int rr = wid * 32 + mi * 16 + lr;
#pragma unroll
    for (int kk = 0; kk < 2; ++kk) {
      f16x8 af = *(const f16x8*)&Ts[rr * 64 + (((q4 + 4 * kk) ^ (rr & 7)) << 3)];
#pragma unroll
      for (int ni = 0; ni < 4; ++ni)
        acc[mi][ni] = __builtin_amdgcn_mfma_f32_16x16x32_f16(af, bfr[ni][kk], acc[mi][ni], 0, 0, 0);
    }
  }
  // transposed restage: Ls[h'][chl], with relu
#pragma unroll
  for (int mi = 0; mi < 2; ++mi)
#pragma unroll
    for (int ni = 0; ni < 4; ++ni)
#pragma unroll
      for (int rr = 0; rr < 4; ++rr) {
        float v = acc[mi][ni][rr];
        Ls[(ni * 16 + lr) * 136 + wid * 32 + mi * 16 + q4 * 4 + rr] =
            (_Float16)(v > 0.f ? v : 0.f);
      }
  __syncthreads();
  _Float16* gb = ght + (size_t)b * PIX * 512 + ct * 128;
#pragma unroll
  for (int it = 0; it < 4; ++it) {
    int idx = it * 256 + t;
    int hp = idx >> 4, cc = (idx & 15) << 3;
    *(f16x8*)&gb[((size_t)hp * 64 + w) * 512 + cc] = *(const f16x8*)&Ls[hp * 136 + cc];
  }
}

// ---- 64x64 per-image fp16 transpose ---- grid (nb*nc) block 256
__global__ __launch_bounds__(256) void k_t16(const _Float16* __restrict__ in,
                                             _Float16* __restrict__ out) {
  __shared__ _Float16 tile[64][65];
  int img = blockIdx.x;
  const _Float16* ip = in + (size_t)img * PIX;
  _Float16* op = out + (size_t)img * PIX;
  int t = threadIdx.x;
  int col = t & 63, r0 = t >> 6;
  for (int it = 0; it < 16; ++it) {
    int r = r0 + it * 4;
    tile[r][col] = ip[r * 64 + col];
  }
  __syncthreads();
  for (int it = 0; it < 16; ++it) {
    int r = r0 + it * 4;
    op[r * 64 + col] = tile[col][r];
  }
}

extern "C" void kernel_launch(void* const* d_in, const int* in_sizes, int n_in,
                              void* d_out, int out_size, void* d_ws, size_t ws_size,
                              hipStream_t stream) {
  const float* x      = (const float*)d_in[0];
  const float* qk_w   = (const float*)d_in[1];
  const float* qk_b   = (const float*)d_in[2];
  const float* dws_w  = (const float*)d_in[3];
  const float* dws_b  = (const float*)d_in[4];
  const float* vs_w   = (const float*)d_in[5];
  const float* vs_b   = (const float*)d_in[6];
  const float* proj_w = (const float*)d_in[7];
  const float* proj_b = (const float*)d_in[8];
  const float* bias_h = (const float*)d_in[9];
  const float* bias_w = (const float*)d_in[10];

  float* ws = (float*)d_ws;
  float* dout = (float*)d_out;

  // ws layout (float units):
  _Float16* xh    = (_Float16*)ws;                 // [0,33.5M fl) x^T fp16; reused as ght
  _Float16* ght   = xh;
  float*    feat  = ws + 33554432;                 // [33.5M,67.1M fl) fp32; reused as tT
  _Float16* tT    = (_Float16*)(ws + 33554432);
  _Float16* attnW = (_Float16*)(ws + 67108864);    // 8.4M halves
  _Float16* attnH = (_Float16*)(ws + 71303168);    // 8.4M halves
  _Float16* qkw_h  = (_Float16*)(ws + 75497472);
  _Float16* wbig_h = (_Float16*)(ws + 75563008);
  _Float16* pjw_h  = (_Float16*)(ws + 75694080);

  // d_out phase scratch:
  float*    qconv = dout;                          // [0,16.8M fl)
  _Float16* qh    = (_Float16*)(dout + 16777216);
  _Float16* kh    = (_Float16*)(dout + 25165824);
  _Float16* Vh    = (_Float16*)(dout + 33554432);  // 67.1M halves

  k_cvt<<<dim3(512), 256, 0, stream>>>(qk_w, qkw_h, 131072);
  k_cvt<<<dim3(1024), 256, 0, stream>>>(proj_w, pjw_h, 262144);
  k_build_wbig<<<512, 256, 0, stream>>>(vs_w, wbig_h);
  k_xt<<<dim3(64, 8, 32), 256, 0, stream>>>(x, xh);
  // feat = qk_w @ x + qk_b (fp32)
  k_mgemm2<<<2048, 256, 0, stream>>>(qkw_h, xh, qk_b, feat, nullptr, 256, 0, 0, 2);
  k_dwconv<<<dim3(128, 32), 256, 0, stream>>>(feat, dws_w, dws_b, qconv);
  k_qkt<<<dim3(64, 32), 256, 0, stream>>>(qconv, 128L * PIX, 0, qh);
  k_qkt<<<dim3(64, 32), 256, 0, stream>>>(feat, 256L * PIX, 128, kh);
  k_mattn<<<dim3(64, 32, 2), 256, 0, stream>>>(qh, kh, bias_w, bias_h, attnW, attnH);
  // V = Wbig @ x + vs_b (triangular, fp16)
  k_mgemm2<<<4096, 256, 0, stream>>>(wbig_h, xh, vs_b, nullptr, Vh, 512, 1, 1, 4);
  // t = attnW ⊙ V (in place, slab-batched MFMA)
  k_smix<<<8192, 256, 0, stream>>>(Vh, attnW);
  // tT = transpose(t)
  k_t16<<<32 * 512, 256, 0, stream>>>(Vh, tT);
  // ght = relu(attnH ⊙ tT), transposed to [p][512]
  k_hmix<<<8192, 256, 0, stream>>>(tT, attnH, ght);
  // out = proj_w @ g + proj_b (fp32)
  k_mgemm2<<<4096, 256, 0, stream>>>(pjw_h, ght, proj_b, dout, nullptr, 512, 0, 0, 4);
}

// Round 6
// 659.901 us; speedup vs baseline: 1.2583x; 1.1496x over previous
//
#include <hip/hip_runtime.h>

#define PIX 4096
#define SCALE 0.25f

typedef _Float16 f16x8 __attribute__((ext_vector_type(8)));
typedef float f32x4 __attribute__((ext_vector_type(4)));

__device__ inline void gload_lds16(const _Float16* g, _Float16* l) {
  __builtin_amdgcn_global_load_lds((const __attribute__((address_space(1))) void*)g,
                                   (__attribute__((address_space(3))) void*)l, 16, 0, 0);
}

// ---- elementwise fp32 -> fp16 ----
__global__ __launch_bounds__(256) void k_cvt(const float* __restrict__ in,
                                             _Float16* __restrict__ out, int n) {
  int i = blockIdx.x * 256 + threadIdx.x;
  if (i < n) out[i] = (_Float16)in[i];
}

// ---- Wbig: block-lower-triangular cascade weight (512x512), fp16 ----
__global__ __launch_bounds__(256) void k_build_wbig(const float* __restrict__ vs_w,
                                                    _Float16* __restrict__ Wbig) {
  int row = blockIdx.x;
  int i = row >> 6, d = row & 63;
  for (int col = threadIdx.x; col < 512; col += 256) {
    int j = col >> 6, c = col & 63;
    Wbig[row * 512 + col] = (j <= i) ? (_Float16)vs_w[i * 4096 + d * 64 + c] : (_Float16)0;
  }
}

// ---- x [b][512][4096] fp32 -> xh [b][4096][512] fp16 ---- grid (64,8,32)
__global__ __launch_bounds__(256) void k_xt(const float* __restrict__ x,
                                            _Float16* __restrict__ xh) {
  __shared__ float tile[64][65];
  int b = blockIdx.z, k0 = blockIdx.y * 64, p0 = blockIdx.x * 64;
  const float* xp = x + ((size_t)b * 512 + k0) * PIX + p0;
  _Float16* out = xh + (size_t)b * PIX * 512;
  int t = threadIdx.x;
  int r = t >> 4, c4 = (t & 15) << 2;
#pragma unroll
  for (int it = 0; it < 4; ++it) {
    float4 v = *(const float4*)&xp[(size_t)(r + it * 16) * PIX + c4];
    tile[r + it * 16][c4 + 0] = v.x; tile[r + it * 16][c4 + 1] = v.y;
    tile[r + it * 16][c4 + 2] = v.z; tile[r + it * 16][c4 + 3] = v.w;
  }
  __syncthreads();
  int pr = t >> 5, kk = (t & 31) << 1;
#pragma unroll
  for (int it = 0; it < 8; ++it) {
    int p = pr + it * 8;
    union { _Float16 h[2]; unsigned int u; } pk;
    pk.h[0] = (_Float16)tile[kk][p]; pk.h[1] = (_Float16)tile[kk + 1][p];
    *(unsigned int*)&out[(size_t)(p0 + p) * 512 + k0 + kk] = pk.u;
  }
}

// ---- 2-phase MFMA GEMM with fused epilogues ----
// C[b][m][p] = sum_k A[m][k]*B[b][p][k] + bias[m]
// MODE 0: fp32 out (proj, M=512). MODE 1: triangular V-GEMM + fused w-attn mix,
// fp16 out = t tiles. MODE 2: feat — mb0 -> fp32 feat[128ch], mb1 -> kh fp16 [p][128c].
// flat grid nwg = 32 * nwg_m * 32 (nwg%8==0), XCD-swizzled, mb fastest.
template<int MODE>
__global__ __launch_bounds__(256) void k_mgemm2(const _Float16* __restrict__ A,
                                                const _Float16* __restrict__ B,
                                                const float* __restrict__ bias,
                                                const _Float16* __restrict__ attn,
                                                float* C, _Float16* H, int nwg_m) {
  __shared__ __align__(16) char smem[34816];
  _Float16* As = (_Float16*)smem;          // [2][4096]
  _Float16* Bs = As + 8192;                // [2][4096]
  int nwg = gridDim.x;
  int id = blockIdx.x;
  int qq = nwg >> 3;
  id = (id & 7) * qq + (id >> 3);          // bijective XCD swizzle
  int mb = id % nwg_m;
  int rest = id / nwg_m;
  int pb = rest & 31;
  int b  = rest >> 5;
  int m0 = mb * 128, p0 = pb * 128;
  const _Float16* Bb = B + (size_t)b * 2097152;
  int t = threadIdx.x, wid = t >> 6, lane = t & 63;
  int wm = (wid >> 1) * 64, wn = (wid & 1) * 64;
  int lr = lane & 15, q = lane >> 4;
  f32x4 acc[4][4] = {};
  int kend = (MODE == 1) ? (m0 + 128) : 512;
  int nt = kend >> 5;
  int L0 = wid * 64 + lane, r0 = L0 >> 2, c0 = (L0 & 3) ^ ((r0 >> 1) & 3);
  int L1 = (4 + wid) * 64 + lane, r1 = L1 >> 2, c1 = (L1 & 3) ^ ((r1 >> 1) & 3);
  const _Float16* Ab = A + (size_t)m0 * 512;
  const _Float16* Bp = Bb + (size_t)p0 * 512;
  size_t ga0 = (size_t)r0 * 512 + c0 * 8, ga1 = (size_t)r1 * 512 + c1 * 8;
  gload_lds16(Ab + ga0, &As[wid * 512]);
  gload_lds16(Ab + ga1, &As[(4 + wid) * 512]);
  gload_lds16(Bp + ga0, &Bs[wid * 512]);
  gload_lds16(Bp + ga1, &Bs[(4 + wid) * 512]);
  __syncthreads();
  int cur = 0;
  for (int tt = 0; tt < nt; ++tt) {
    if (tt + 1 < nt) {
      int k0 = (tt + 1) << 5;
      gload_lds16(Ab + ga0 + k0, &As[(cur ^ 1) * 4096 + wid * 512]);
      gload_lds16(Ab + ga1 + k0, &As[(cur ^ 1) * 4096 + (4 + wid) * 512]);
      gload_lds16(Bp + ga0 + k0, &Bs[(cur ^ 1) * 4096 + wid * 512]);
      gload_lds16(Bp + ga1 + k0, &Bs[(cur ^ 1) * 4096 + (4 + wid) * 512]);
    }
    f16x8 af[4], bf_[4];
#pragma unroll
    for (int mi = 0; mi < 4; ++mi) {
      int rr = wm + mi * 16 + lr;
      af[mi] = *(const f16x8*)&As[cur * 4096 + rr * 32 + ((q ^ ((rr >> 1) & 3)) << 3)];
    }
#pragma unroll
    for (int ni = 0; ni < 4; ++ni) {
      int rr = wn + ni * 16 + lr;
      bf_[ni] = *(const f16x8*)&Bs[cur * 4096 + rr * 32 + ((q ^ ((rr >> 1) & 3)) << 3)];
    }
#pragma unroll
    for (int mi = 0; mi < 4; ++mi)
#pragma unroll
      for (int ni = 0; ni < 4; ++ni)
        acc[mi][ni] = __builtin_amdgcn_mfma_f32_16x16x32_f16(af[mi], bf_[ni], acc[mi][ni], 0, 0, 0);
    __syncthreads();
    cur ^= 1;
  }

  if (MODE == 0) {
#pragma unroll
    for (int mi = 0; mi < 4; ++mi)
#pragma unroll
      for (int rr = 0; rr < 4; ++rr) {
        int m = m0 + wm + mi * 16 + q * 4 + rr;
        float bi = bias[m];
        float* crow = C + ((size_t)b * 512 + m) * PIX + p0 + wn;
#pragma unroll
        for (int ni = 0; ni < 4; ++ni)
          crow[ni * 16 + lr] = acc[mi][ni][rr] + bi;
      }
  }

  if (MODE == 1) {
    // fused w-attn mix: t[m][q'] = sum_k (C[m][k]+bias) * attn[q'][k], slab-local
    _Float16* Cs = (_Float16*)smem + wid * 4096;   // per-wave 64x64 halves
    int s = (p0 >> 6) + (wn >> 6);                 // h-slab of this wave
    const _Float16* Ab2 = attn + ((size_t)b * 64 + s) * 4096;
    f16x8 bfr[4][2];
#pragma unroll
    for (int ni = 0; ni < 4; ++ni)
#pragma unroll
      for (int kk = 0; kk < 2; ++kk)
        bfr[ni][kk] = *(const f16x8*)&Ab2[(ni * 16 + lr) * 64 + q * 8 + kk * 32];
#pragma unroll
    for (int mi = 0; mi < 4; ++mi)
#pragma unroll
      for (int ni = 0; ni < 4; ++ni)
#pragma unroll
        for (int rr = 0; rr < 4; ++rr) {
          int row = mi * 16 + q * 4 + rr, col = ni * 16 + lr;
          Cs[row * 64 + ((((col >> 3) ^ (row & 7)) << 3) | (col & 7))] =
              (_Float16)(acc[mi][ni][rr] + bias[m0 + wm + row]);
        }
    f32x4 acc2[4][4] = {};
#pragma unroll
    for (int mi2 = 0; mi2 < 4; ++mi2)
#pragma unroll
      for (int kk = 0; kk < 2; ++kk) {
        f16x8 afr = *(const f16x8*)&Cs[(mi2 * 16 + lr) * 64 + (((q + kk * 4) ^ (lr & 7)) << 3)];
#pragma unroll
        for (int ni2 = 0; ni2 < 4; ++ni2)
          acc2[mi2][ni2] = __builtin_amdgcn_mfma_f32_16x16x32_f16(afr, bfr[ni2][kk], acc2[mi2][ni2], 0, 0, 0);
      }
#pragma unroll
    for (int mi2 = 0; mi2 < 4; ++mi2)
#pragma unroll
      for (int rr = 0; rr < 4; ++rr) {
        int m = m0 + wm + mi2 * 16 + q * 4 + rr;
        _Float16* crow = H + ((size_t)b * 512 + m) * PIX + p0 + wn;
#pragma unroll
        for (int ni2 = 0; ni2 < 4; ++ni2)
          crow[ni2 * 16 + lr] = (_Float16)acc2[mi2][ni2][rr];
      }
  }

  if (MODE == 2) {
    if (mb == 0) {                         // q-half fp32 for dwconv
#pragma unroll
      for (int mi = 0; mi < 4; ++mi)
#pragma unroll
        for (int rr = 0; rr < 4; ++rr) {
          int m = wm + mi * 16 + q * 4 + rr;
          float bi = bias[m];
          float* crow = C + ((size_t)b * 128 + m) * PIX + p0 + wn;
#pragma unroll
          for (int ni = 0; ni < 4; ++ni)
            crow[ni * 16 + lr] = acc[mi][ni][rr] + bi;
        }
    } else {                               // k-half -> kh fp16 [p][128c]
      _Float16* Ts = (_Float16*)smem;      // [128][136]
#pragma unroll
      for (int mi = 0; mi < 4; ++mi)
#pragma unroll
        for (int ni = 0; ni < 4; ++ni)
#pragma unroll
          for (int rr = 0; rr < 4; ++rr) {
            int row = mi * 16 + q * 4 + rr;            // local ch
            Ts[(wn + ni * 16 + lr) * 136 + wm + row] =
                (_Float16)(acc[mi][ni][rr] + bias[m0 + wm + row]);
          }
      __syncthreads();
      _Float16* khb = H + ((size_t)b * PIX + p0) * 128;
#pragma unroll
      for (int it = 0; it < 8; ++it) {
        int idx = it * 256 + t;
        int row = idx >> 4, cc = (idx & 15) << 3;
        *(f16x8*)&khb[(size_t)row * 128 + cc] = *(const f16x8*)&Ts[row * 136 + cc];
      }
    }
  }
}

// ---- depthwise 5x5 SAME conv on q-feat [b][128][PIX] ---- grid (128, B)
__global__ __launch_bounds__(256) void k_dwconv(const float* __restrict__ feat,
                                                const float* __restrict__ w,
                                                const float* __restrict__ bias,
                                                float* __restrict__ qconv) {
  __shared__ float tile[68][68];
  int c = blockIdx.x, b = blockIdx.y;
  const float* in = feat + ((size_t)b * 128 + c) * PIX;
  float wreg[25];
#pragma unroll
  for (int i = 0; i < 25; ++i) wreg[i] = w[c * 25 + i];
  float bi = bias[c];
  int t = threadIdx.x;
  for (int idx = t; idx < 68 * 68; idx += 256) {
    int y = idx / 68, xx = idx - y * 68;
    int h = y - 2, ww = xx - 2;
    float v = 0.f;
    if (h >= 0 && h < 64 && ww >= 0 && ww < 64) v = in[h * 64 + ww];
    tile[y][xx] = v;
  }
  __syncthreads();
  float* out = qconv + ((size_t)b * 128 + c) * PIX;
  int tx = (t & 15) << 2, ty = (t >> 4) << 2;
#pragma unroll
  for (int i = 0; i < 4; ++i) {
    float4 o;
    float* po = (float*)&o;
#pragma unroll
    for (int j = 0; j < 4; ++j) {
      float s = bi;
#pragma unroll
      for (int dy = 0; dy < 5; ++dy)
#pragma unroll
        for (int dx = 0; dx < 5; ++dx)
          s += wreg[dy * 5 + dx] * tile[ty + i + dy][tx + j + dx];
      po[j] = s;
    }
    *(float4*)&out[(ty + i) * 64 + tx] = o;
  }
}

// ---- fp32 [128c][4096p] -> fp16 [4096p][128c] ---- grid (64,32)
__global__ __launch_bounds__(256) void k_qkt(const float* __restrict__ in, long ibs, int ic0,
                                             _Float16* __restrict__ out) {
  __shared__ __align__(16) _Float16 Ts[64 * 136];
  int p0 = blockIdx.x * 64, b = blockIdx.y;
  const float* ip = in + (size_t)b * ibs + (size_t)ic0 * PIX;
  int t = threadIdx.x;
#pragma unroll
  for (int it = 0; it < 8; ++it) {
    int i4 = it * 256 + t;
    int c = i4 >> 4, pp = (i4 & 15) << 2;
    float4 v = *(const float4*)&ip[(size_t)c * PIX + p0 + pp];
    Ts[(pp + 0) * 136 + c] = (_Float16)v.x;
    Ts[(pp + 1) * 136 + c] = (_Float16)v.y;
    Ts[(pp + 2) * 136 + c] = (_Float16)v.z;
    Ts[(pp + 3) * 136 + c] = (_Float16)v.w;
  }
  __syncthreads();
  _Float16* op = out + (size_t)b * (PIX * 128) + (size_t)p0 * 128;
#pragma unroll
  for (int it = 0; it < 4; ++it) {
    int ch = it * 256 + t;
    int p = ch >> 4, cc = (ch & 15) << 3;
    *(f16x8*)&op[p * 128 + cc] = *(const f16x8*)&Ts[p * 136 + cc];
  }
}

// ---- MFMA attention scores+softmax -> fp16 attn [b][j][q][k] ---- grid (64,32,2)
__global__ __launch_bounds__(256) void k_mattn(const _Float16* __restrict__ qh,
                                               const _Float16* __restrict__ kh,
                                               const float* __restrict__ bias_w,
                                               const float* __restrict__ bias_h,
                                               _Float16* __restrict__ attnW,
                                               _Float16* __restrict__ attnH) {
  __shared__ __align__(16) _Float16 Qs[64 * 136];
  __shared__ __align__(16) _Float16 Ks[64 * 136];
  __shared__ float bl[64];
  int j = blockIdx.x, b = blockIdx.y, which = blockIdx.z;
  const float* bias = which ? bias_h : bias_w;
  _Float16* attn = which ? attnH : attnW;
  int t = threadIdx.x;
  if (t < 64) bl[t] = bias[t];
  const _Float16* qb = qh + (size_t)b * (PIX * 128);
  const _Float16* kb = kh + (size_t)b * (PIX * 128);
#pragma unroll
  for (int it = 0; it < 4; ++it) {
    int idx = it * 256 + t;
    int r = idx >> 4, cc = (idx & 15) << 3;
    size_t p = which ? (size_t)(j + 64 * r) : (size_t)(j * 64 + r);
    *(f16x8*)&Qs[r * 136 + cc] = *(const f16x8*)&qb[p * 128 + cc];
    *(f16x8*)&Ks[r * 136 + cc] = *(const f16x8*)&kb[p * 128 + cc];
  }
  __syncthreads();
  int wave = t >> 6, lane = t & 63;
  int lr = lane & 15, q4 = lane >> 4;
  f16x8 af[4];
#pragma unroll
  for (int kk = 0; kk < 4; ++kk)
    af[kk] = *(const f16x8*)&Qs[(wave * 16 + lr) * 136 + q4 * 8 + kk * 32];
  f32x4 acc[4] = {};
#pragma unroll
  for (int ni = 0; ni < 4; ++ni)
#pragma unroll
    for (int kk = 0; kk < 4; ++kk) {
      f16x8 bf = *(const f16x8*)&Ks[(ni * 16 + lr) * 136 + q4 * 8 + kk * 32];
      acc[ni] = __builtin_amdgcn_mfma_f32_16x16x32_f16(af[kk], bf, acc[ni], 0, 0, 0);
    }
  float ev[4][4], sm[4];
#pragma unroll
  for (int r = 0; r < 4; ++r) {
    int qrow = wave * 16 + q4 * 4 + r;
    float m = -1e30f;
#pragma unroll
    for (int ni = 0; ni < 4; ++ni) {
      int k = ni * 16 + lr;
      ev[ni][r] = acc[ni][r] * SCALE + bl[abs(qrow - k)];
      m = fmaxf(m, ev[ni][r]);
    }
    m = fmaxf(m, __shfl_xor(m, 1)); m = fmaxf(m, __shfl_xor(m, 2));
    m = fmaxf(m, __shfl_xor(m, 4)); m = fmaxf(m, __shfl_xor(m, 8));
    float s = 0.f;
#pragma unroll
    for (int ni = 0; ni < 4; ++ni) { ev[ni][r] = __expf(ev[ni][r] - m); s += ev[ni][r]; }
    s += __shfl_xor(s, 1); s += __shfl_xor(s, 2);
    s += __shfl_xor(s, 4); s += __shfl_xor(s, 8);
    sm[r] = 1.f / s;
  }
  _Float16* ab = attn + (((size_t)b * 64 + j) * 64) * 64;
#pragma unroll
  for (int r = 0; r < 4; ++r) {
    int qrow = wave * 16 + q4 * 4 + r;
#pragma unroll
    for (int ni = 0; ni < 4; ++ni)
      ab[qrow * 64 + ni * 16 + lr] = (_Float16)(ev[ni][r] * sm[r]);
  }
}

// ---- h-mix + relu + transposed write to ght ---- grid flat 8192
__global__ __launch_bounds__(256) void k_hmix(const _Float16* __restrict__ tT,
                                              const _Float16* __restrict__ attnH,
                                              _Float16* __restrict__ ght) {
  __shared__ __align__(16) _Float16 Ts[128 * 64];
  __shared__ __align__(16) _Float16 Ls[64 * 136];
  int id = blockIdx.x;
  int ct = id & 3, w = (id >> 2) & 63, b = id >> 8;
  int t = threadIdx.x, wid = t >> 6, lane = t & 63;
  int lr = lane & 15, q4 = lane >> 4;
  const _Float16* Tb = tT + ((size_t)b * 512 + ct * 128) * PIX + w * 64;
#pragma unroll
  for (int it = 0; it < 4; ++it) {
    int idx = it * 256 + t;
    int row = idx >> 3, c = idx & 7;
    int sc = c ^ (row & 7);
    gload_lds16(Tb + (size_t)row * PIX + sc * 8, &Ts[(it * 256 + wid * 64) * 8]);
  }
  const _Float16* Ab = attnH + ((size_t)b * 64 + w) * 4096;
  f16x8 bfr[4][2];
#pragma unroll
  for (int ni = 0; ni < 4; ++ni)
#pragma unroll
    for (int kk = 0; kk < 2; ++kk)
      bfr[ni][kk] = *(const f16x8*)&Ab[(ni * 16 + lr) * 64 + q4 * 8 + kk * 32];
  __syncthreads();
  f32x4 acc[2][4] = {};
#pragma unroll
  for (int mi = 0; mi < 2; ++mi) {
    int rr = wid * 32 + mi * 16 + lr;
#pragma unroll
    for (int kk = 0; kk < 2; ++kk) {
      f16x8 af = *(const f16x8*)&Ts[rr * 64 + (((q4 + 4 * kk) ^ (rr & 7)) << 3)];
#pragma unroll
      for (int ni = 0; ni < 4; ++ni)
        acc[mi][ni] = __builtin_amdgcn_mfma_f32_16x16x32_f16(af, bfr[ni][kk], acc[mi][ni], 0, 0, 0);
    }
  }
#pragma unroll
  for (int mi = 0; mi < 2; ++mi)
#pragma unroll
    for (int ni = 0; ni < 4; ++ni)
#pragma unroll
      for (int rr = 0; rr < 4; ++rr) {
        float v = acc[mi][ni][rr];
        Ls[(ni * 16 + lr) * 136 + wid * 32 + mi * 16 + q4 * 4 + rr] =
            (_Float16)(v > 0.f ? v : 0.f);
      }
  __syncthreads();
  _Float16* gb = ght + (size_t)b * PIX * 512 + ct * 128;
#pragma unroll
  for (int it = 0; it < 4; ++it) {
    int idx = it * 256 + t;
    int hp = idx >> 4, cc = (idx & 15) << 3;
    *(f16x8*)&gb[((size_t)hp * 64 + w) * 512 + cc] = *(const f16x8*)&Ls[hp * 136 + cc];
  }
}

// ---- 64x64 per-image fp16 transpose ---- grid (nb*nc)
__global__ __launch_bounds__(256) void k_t16(const _Float16* __restrict__ in,
                                             _Float16* __restrict__ out) {
  __shared__ _Float16 tile[64][65];
  int img = blockIdx.x;
  const _Float16* ip = in + (size_t)img * PIX;
  _Float16* op = out + (size_t)img * PIX;
  int t = threadIdx.x;
  int col = t & 63, r0 = t >> 6;
  for (int it = 0; it < 16; ++it) {
    int r = r0 + it * 4;
    tile[r][col] = ip[r * 64 + col];
  }
  __syncthreads();
  for (int it = 0; it < 16; ++it) {
    int r = r0 + it * 4;
    op[r * 64 + col] = tile[col][r];
  }
}

extern "C" void kernel_launch(void* const* d_in, const int* in_sizes, int n_in,
                              void* d_out, int out_size, void* d_ws, size_t ws_size,
                              hipStream_t stream) {
  const float* x      = (const float*)d_in[0];
  const float* qk_w   = (const float*)d_in[1];
  const float* qk_b   = (const float*)d_in[2];
  const float* dws_w  = (const float*)d_in[3];
  const float* dws_b  = (const float*)d_in[4];
  const float* vs_w   = (const float*)d_in[5];
  const float* vs_b   = (const float*)d_in[6];
  const float* proj_w = (const float*)d_in[7];
  const float* proj_b = (const float*)d_in[8];
  const float* bias_h = (const float*)d_in[9];
  const float* bias_w = (const float*)d_in[10];

  float* ws = (float*)d_ws;
  float* dout = (float*)d_out;

  // ws layout (float units):
  _Float16* xh    = (_Float16*)ws;                 // [0,33.5M fl); reused as ght
  _Float16* ght   = xh;
  float*    feat  = ws + 33554432;                 // [33.5M,50.3M fl) fp32 q-half
  _Float16* tT    = (_Float16*)(ws + 33554432);    // reuses feat region (+more)
  _Float16* attnW = (_Float16*)(ws + 67108864);
  _Float16* attnH = (_Float16*)(ws + 71303168);
  _Float16* qkw_h  = (_Float16*)(ws + 75497472);
  _Float16* wbig_h = (_Float16*)(ws + 75563008);
  _Float16* pjw_h  = (_Float16*)(ws + 75694080);

  // d_out phase scratch:
  float*    qconv = dout;                          // [0,16.8M fl)
  _Float16* qh    = (_Float16*)(dout + 16777216);
  _Float16* kh    = (_Float16*)(dout + 25165824);
  _Float16* Vh    = (_Float16*)(dout + 33554432);  // t tiles (67.1M halves)

  k_cvt<<<dim3(512), 256, 0, stream>>>(qk_w, qkw_h, 131072);
  k_cvt<<<dim3(1024), 256, 0, stream>>>(proj_w, pjw_h, 262144);
  k_build_wbig<<<512, 256, 0, stream>>>(vs_w, wbig_h);
  k_xt<<<dim3(64, 8, 32), 256, 0, stream>>>(x, xh);
  // feat GEMM: q-half fp32 + kh fp16 fused
  k_mgemm2<2><<<2048, 256, 0, stream>>>(qkw_h, xh, qk_b, nullptr, feat, kh, 2);
  k_dwconv<<<dim3(128, 32), 256, 0, stream>>>(feat, dws_w, dws_b, qconv);
  k_qkt<<<dim3(64, 32), 256, 0, stream>>>(qconv, 128L * PIX, 0, qh);
  k_mattn<<<dim3(64, 32, 2), 256, 0, stream>>>(qh, kh, bias_w, bias_h, attnW, attnH);
  // V GEMM (triangular) + fused w-attn mix -> t
  k_mgemm2<1><<<4096, 256, 0, stream>>>(wbig_h, xh, vs_b, attnW, nullptr, Vh, 4);
  // tT = transpose(t)
  k_t16<<<32 * 512, 256, 0, stream>>>(Vh, tT);
  // ght = relu(attnH ⊙ tT), transposed to [p][512]
  k_hmix<<<8192, 256, 0, stream>>>(tT, attnH, ght);
  // out = proj_w @ g + proj_b (fp32)
  k_mgemm2<0><<<4096, 256, 0, stream>>>(pjw_h, ght, proj_b, nullptr, dout, nullptr, 4);
}

// Round 7
// 601.481 us; speedup vs baseline: 1.3805x; 1.0971x over previous
//
#include <hip/hip_runtime.h>

#define PIX 4096
#define SCALE 0.25f

typedef _Float16 f16x8 __attribute__((ext_vector_type(8)));
typedef float f32x4 __attribute__((ext_vector_type(4)));

__device__ inline void gload_lds16(const _Float16* g, _Float16* l) {
  __builtin_amdgcn_global_load_lds((const __attribute__((address_space(1))) void*)g,
                                   (__attribute__((address_space(3))) void*)l, 16, 0, 0);
}

// ---- elementwise fp32 -> fp16 ----
__global__ __launch_bounds__(256) void k_cvt(const float* __restrict__ in,
                                             _Float16* __restrict__ out, int n) {
  int i = blockIdx.x * 256 + threadIdx.x;
  if (i < n) out[i] = (_Float16)in[i];
}

// ---- Wbig: block-lower-triangular cascade weight (512x512), fp16 ----
__global__ __launch_bounds__(256) void k_build_wbig(const float* __restrict__ vs_w,
                                                    _Float16* __restrict__ Wbig) {
  int row = blockIdx.x;
  int i = row >> 6, d = row & 63;
  for (int col = threadIdx.x; col < 512; col += 256) {
    int j = col >> 6, c = col & 63;
    Wbig[row * 512 + col] = (j <= i) ? (_Float16)vs_w[i * 4096 + d * 64 + c] : (_Float16)0;
  }
}

// ---- x [b][512][4096] fp32 -> xh [b][4096][512] fp16 ---- grid (64,8,32)
__global__ __launch_bounds__(256) void k_xt(const float* __restrict__ x,
                                            _Float16* __restrict__ xh) {
  __shared__ float tile[64][65];
  int b = blockIdx.z, k0 = blockIdx.y * 64, p0 = blockIdx.x * 64;
  const float* xp = x + ((size_t)b * 512 + k0) * PIX + p0;
  _Float16* out = xh + (size_t)b * PIX * 512;
  int t = threadIdx.x;
  int r = t >> 4, c4 = (t & 15) << 2;
#pragma unroll
  for (int it = 0; it < 4; ++it) {
    float4 v = *(const float4*)&xp[(size_t)(r + it * 16) * PIX + c4];
    tile[r + it * 16][c4 + 0] = v.x; tile[r + it * 16][c4 + 1] = v.y;
    tile[r + it * 16][c4 + 2] = v.z; tile[r + it * 16][c4 + 3] = v.w;
  }
  __syncthreads();
  int pr = t >> 5, kk = (t & 31) << 1;
#pragma unroll
  for (int it = 0; it < 8; ++it) {
    int p = pr + it * 8;
    union { _Float16 h[2]; unsigned int u; } pk;
    pk.h[0] = (_Float16)tile[kk][p]; pk.h[1] = (_Float16)tile[kk + 1][p];
    *(unsigned int*)&out[(size_t)(p0 + p) * 512 + k0 + kk] = pk.u;
  }
}

// ==== 256x256 8-phase MFMA GEMM, counted-vmcnt pipeline (T2+T3+T4+T5) ====
// C[b][m][p] = sum_k A[m][k]*B[b][p][k] + bias[m]
// 512 threads = 8 waves (2M x 4N), per-wave out 128x64. BK=64, 2 sub-phases/K-tile.
// LDS: 4 group-slots x 32KB (group = A 256x32 + B 256x32 halves of one k-half).
// At sub-phase n: issue group n+3 (slot (n-1)&3, provably free), vmcnt(4r).
// MODE 0: proj, fp32 out, M=512. MODE 1: V triangular + fused w-mix -> t fp16.
// MODE 2: feat, M=256: wm=0 -> fp32 q-feat, wm=1 -> kh fp16 [p][128c].
template<int MODE>
__global__ __launch_bounds__(512, 2) void k_mg8(const _Float16* __restrict__ A,
                                                const _Float16* __restrict__ B,
                                                const float* __restrict__ bias,
                                                const _Float16* __restrict__ attn,
                                                float* C, _Float16* H, int nwg_m) {
  __shared__ __align__(16) _Float16 lds[65536];   // 128 KB
  int nwg = gridDim.x;
  int id = blockIdx.x;
  int qq = nwg >> 3;
  id = (id & 7) * qq + (id >> 3);                 // bijective XCD swizzle (nwg%8==0)
  int mb = id % nwg_m;
  int rest = id / nwg_m;
  int pb = rest & 15;
  int b  = rest >> 4;
  int m0 = mb * 256, p0 = pb * 256;
  int t = threadIdx.x, wid = t >> 6, lane = t & 63;
  int wm = wid >> 2, wn = wid & 3;
  int lr = lane & 15, q4 = lane >> 4;
  const _Float16* Ab = A + (size_t)m0 * 512;
  const _Float16* Bp = B + (size_t)b * 2097152 + (size_t)p0 * 512;

  int nt = (MODE == 1) ? ((m0 + 256) >> 6) : 8;   // K-tiles of 64
  int nsub = nt * 2;

  auto STAGE = [&](int g) {
    int slot = g & 3;
    _Float16* dA = lds + slot * 16384;
    _Float16* dB = dA + 8192;
    size_t ks = (size_t)g * 32;
#pragma unroll
    for (int is = 0; is < 2; ++is) {
      int L = is * 512 + wid * 64 + lane;
      int row = L >> 2, sl = L & 3;
      int c = sl ^ ((row >> 1) & 3);
      gload_lds16(Ab + (size_t)row * 512 + ks + c * 8, dA + (size_t)(is * 512 + wid * 64) * 8);
      gload_lds16(Bp + (size_t)row * 512 + ks + c * 8, dB + (size_t)(is * 512 + wid * 64) * 8);
    }
  };

  f32x4 acc[8][4] = {};
  STAGE(0); STAGE(1); STAGE(2);
  for (int n = 0; n < nsub; ++n) {
    if (n + 3 < nsub) STAGE(n + 3);
    int r = nsub - 1 - n; if (r > 3) r = 3;
    if (r == 3)      asm volatile("s_waitcnt vmcnt(12)" ::: "memory");
    else if (r == 2) asm volatile("s_waitcnt vmcnt(8)" ::: "memory");
    else if (r == 1) asm volatile("s_waitcnt vmcnt(4)" ::: "memory");
    else             asm volatile("s_waitcnt vmcnt(0)" ::: "memory");
    __builtin_amdgcn_s_barrier();
    const _Float16* A_s = lds + (n & 3) * 16384;
    const _Float16* B_s = A_s + 8192;
    f16x8 af[8], bf[4];
#pragma unroll
    for (int mi = 0; mi < 8; ++mi) {
      int row = wm * 128 + mi * 16 + lr;
      af[mi] = *(const f16x8*)&A_s[row * 32 + ((q4 ^ ((row >> 1) & 3)) << 3)];
    }
#pragma unroll
    for (int ni = 0; ni < 4; ++ni) {
      int row = wn * 64 + ni * 16 + lr;
      bf[ni] = *(const f16x8*)&B_s[row * 32 + ((q4 ^ ((row >> 1) & 3)) << 3)];
    }
    __builtin_amdgcn_s_setprio(1);
#pragma unroll
    for (int mi = 0; mi < 8; ++mi)
#pragma unroll
      for (int ni = 0; ni < 4; ++ni)
        acc[mi][ni] = __builtin_amdgcn_mfma_f32_16x16x32_f16(af[mi], bf[ni], acc[mi][ni], 0, 0, 0);
    __builtin_amdgcn_s_setprio(0);
    __builtin_amdgcn_s_barrier();
  }

  if (MODE == 0) {
#pragma unroll
    for (int mi = 0; mi < 8; ++mi)
#pragma unroll
      for (int rr = 0; rr < 4; ++rr) {
        int m = m0 + wm * 128 + mi * 16 + q4 * 4 + rr;
        float bi = bias[m];
        float* crow = C + ((size_t)b * 512 + m) * PIX + p0 + wn * 64;
#pragma unroll
        for (int ni = 0; ni < 4; ++ni)
          crow[ni * 16 + lr] = acc[mi][ni][rr] + bi;
      }
  }

  if (MODE == 1) {
    // fused w-mix: t[m][q'] = sum_k (C[m][k]+bias) * attnW[s][q',k]; wave's 64-p
    // range == one h-slab. Restage C to per-wave LDS zone (swizzled), 64 MFMAs.
    _Float16* Cs = lds + wid * 8192;               // 128 x 64 halves
#pragma unroll
    for (int mi = 0; mi < 8; ++mi)
#pragma unroll
      for (int ni = 0; ni < 4; ++ni)
#pragma unroll
        for (int rr = 0; rr < 4; ++rr) {
          int row = mi * 16 + q4 * 4 + rr;
          int col = ni * 16 + lr;
          Cs[row * 64 + ((((col >> 3) ^ (row & 7)) << 3) | (col & 7))] =
              (_Float16)(acc[mi][ni][rr] + bias[m0 + wm * 128 + row]);
        }
    int s = pb * 4 + wn;
    const _Float16* Ab2 = attn + ((size_t)b * 64 + s) * 4096;
    f16x8 bfr[4][2];
#pragma unroll
    for (int ni = 0; ni < 4; ++ni)
#pragma unroll
      for (int kk = 0; kk < 2; ++kk)
        bfr[ni][kk] = *(const f16x8*)&Ab2[(ni * 16 + lr) * 64 + q4 * 8 + kk * 32];
    f32x4 acc2[8][4] = {};
#pragma unroll
    for (int mi2 = 0; mi2 < 8; ++mi2)
#pragma unroll
      for (int kk = 0; kk < 2; ++kk) {
        int row = mi2 * 16 + lr;
        f16x8 afr = *(const f16x8*)&Cs[row * 64 + (((q4 + kk * 4) ^ (row & 7)) << 3)];
#pragma unroll
        for (int ni2 = 0; ni2 < 4; ++ni2)
          acc2[mi2][ni2] = __builtin_amdgcn_mfma_f32_16x16x32_f16(afr, bfr[ni2][kk], acc2[mi2][ni2], 0, 0, 0);
      }
#pragma unroll
    for (int mi2 = 0; mi2 < 8; ++mi2)
#pragma unroll
      for (int rr = 0; rr < 4; ++rr) {
        int m = m0 + wm * 128 + mi2 * 16 + q4 * 4 + rr;
        _Float16* crow = H + ((size_t)b * 512 + m) * PIX + p0 + wn * 64;
#pragma unroll
        for (int ni2 = 0; ni2 < 4; ++ni2)
          crow[ni2 * 16 + lr] = (_Float16)acc2[mi2][ni2][rr];
      }
  }

  if (MODE == 2) {
    if (wm == 0) {                                 // q-half fp32 for dwconv
#pragma unroll
      for (int mi = 0; mi < 8; ++mi)
#pragma unroll
        for (int rr = 0; rr < 4; ++rr) {
          int m = mi * 16 + q4 * 4 + rr;           // 0..127
          float bi = bias[m];
          float* crow = C + ((size_t)b * 128 + m) * PIX + p0 + wn * 64;
#pragma unroll
          for (int ni = 0; ni < 4; ++ni)
            crow[ni * 16 + lr] = acc[mi][ni][rr] + bi;
        }
    } else {                                       // k-half -> kh fp16 [p][128c]
      _Float16* Ls = lds + (size_t)(wid - 4) * 16384;  // 64 x 136 halves
#pragma unroll
      for (int mi = 0; mi < 8; ++mi)
#pragma unroll
        for (int ni = 0; ni < 4; ++ni)
#pragma unroll
          for (int rr = 0; rr < 4; ++rr) {
            int ch = mi * 16 + q4 * 4 + rr;        // 0..127
            Ls[(ni * 16 + lr) * 136 + ch] = (_Float16)(acc[mi][ni][rr] + bias[128 + ch]);
          }
      _Float16* khb = H + ((size_t)b * PIX + p0 + wn * 64) * 128;
#pragma unroll
      for (int it = 0; it < 16; ++it) {
        int chk = it * 64 + lane;
        int prow = chk >> 4, cc = (chk & 15) << 3;
        *(f16x8*)&khb[(size_t)prow * 128 + cc] = *(const f16x8*)&Ls[prow * 136 + cc];
      }
    }
  }
}

// ---- depthwise 5x5 SAME conv on q-feat [b][128][PIX] ---- grid (128, B)
__global__ __launch_bounds__(256) void k_dwconv(const float* __restrict__ feat,
                                                const float* __restrict__ w,
                                                const float* __restrict__ bias,
                                                float* __restrict__ qconv) {
  __shared__ float tile[68][68];
  int c = blockIdx.x, b = blockIdx.y;
  const float* in = feat + ((size_t)b * 128 + c) * PIX;
  float wreg[25];
#pragma unroll
  for (int i = 0; i < 25; ++i) wreg[i] = w[c * 25 + i];
  float bi = bias[c];
  int t = threadIdx.x;
  for (int idx = t; idx < 68 * 68; idx += 256) {
    int y = idx / 68, xx = idx - y * 68;
    int h = y - 2, ww = xx - 2;
    float v = 0.f;
    if (h >= 0 && h < 64 && ww >= 0 && ww < 64) v = in[h * 64 + ww];
    tile[y][xx] = v;
  }
  __syncthreads();
  float* out = qconv + ((size_t)b * 128 + c) * PIX;
  int tx = (t & 15) << 2, ty = (t >> 4) << 2;
#pragma unroll
  for (int i = 0; i < 4; ++i) {
    float4 o;
    float* po = (float*)&o;
#pragma unroll
    for (int j = 0; j < 4; ++j) {
      float s = bi;
#pragma unroll
      for (int dy = 0; dy < 5; ++dy)
#pragma unroll
        for (int dx = 0; dx < 5; ++dx)
          s += wreg[dy * 5 + dx] * tile[ty + i + dy][tx + j + dx];
      po[j] = s;
    }
    *(float4*)&out[(ty + i) * 64 + tx] = o;
  }
}

// ---- fp32 [128c][4096p] -> fp16 [4096p][128c] ---- grid (64,32)
__global__ __launch_bounds__(256) void k_qkt(const float* __restrict__ in, long ibs, int ic0,
                                             _Float16* __restrict__ out) {
  __shared__ __align__(16) _Float16 Ts[64 * 136];
  int p0 = blockIdx.x * 64, b = blockIdx.y;
  const float* ip = in + (size_t)b * ibs + (size_t)ic0 * PIX;
  int t = threadIdx.x;
#pragma unroll
  for (int it = 0; it < 8; ++it) {
    int i4 = it * 256 + t;
    int c = i4 >> 4, pp = (i4 & 15) << 2;
    float4 v = *(const float4*)&ip[(size_t)c * PIX + p0 + pp];
    Ts[(pp + 0) * 136 + c] = (_Float16)v.x;
    Ts[(pp + 1) * 136 + c] = (_Float16)v.y;
    Ts[(pp + 2) * 136 + c] = (_Float16)v.z;
    Ts[(pp + 3) * 136 + c] = (_Float16)v.w;
  }
  __syncthreads();
  _Float16* op = out + (size_t)b * (PIX * 128) + (size_t)p0 * 128;
#pragma unroll
  for (int it = 0; it < 4; ++it) {
    int ch = it * 256 + t;
    int p = ch >> 4, cc = (ch & 15) << 3;
    *(f16x8*)&op[p * 128 + cc] = *(const f16x8*)&Ts[p * 136 + cc];
  }
}

// ---- MFMA attention scores+softmax -> fp16 attn [b][j][q][k] ---- grid (64,32,2)
__global__ __launch_bounds__(256) void k_mattn(const _Float16* __restrict__ qh,
                                               const _Float16* __restrict__ kh,
                                               const float* __restrict__ bias_w,
                                               const float* __restrict__ bias_h,
                                               _Float16* __restrict__ attnW,
                                               _Float16* __restrict__ attnH) {
  __shared__ __align__(16) _Float16 Qs[64 * 136];
  __shared__ __align__(16) _Float16 Ks[64 * 136];
  __shared__ float bl[64];
  int j = blockIdx.x, b = blockIdx.y, which = blockIdx.z;
  const float* bias = which ? bias_h : bias_w;
  _Float16* attn = which ? attnH : attnW;
  int t = threadIdx.x;
  if (t < 64) bl[t] = bias[t];
  const _Float16* qb = qh + (size_t)b * (PIX * 128);
  const _Float16* kb = kh + (size_t)b * (PIX * 128);
#pragma unroll
  for (int it = 0; it < 4; ++it) {
    int idx = it * 256 + t;
    int r = idx >> 4, cc = (idx & 15) << 3;
    size_t p = which ? (size_t)(j + 64 * r) : (size_t)(j * 64 + r);
    *(f16x8*)&Qs[r * 136 + cc] = *(const f16x8*)&qb[p * 128 + cc];
    *(f16x8*)&Ks[r * 136 + cc] = *(const f16x8*)&kb[p * 128 + cc];
  }
  __syncthreads();
  int wave = t >> 6, lane = t & 63;
  int lr = lane & 15, q4 = lane >> 4;
  f16x8 af[4];
#pragma unroll
  for (int kk = 0; kk < 4; ++kk)
    af[kk] = *(const f16x8*)&Qs[(wave * 16 + lr) * 136 + q4 * 8 + kk * 32];
  f32x4 acc[4] = {};
#pragma unroll
  for (int ni = 0; ni < 4; ++ni)
#pragma unroll
    for (int kk = 0; kk < 4; ++kk) {
      f16x8 bf = *(const f16x8*)&Ks[(ni * 16 + lr) * 136 + q4 * 8 + kk * 32];
      acc[ni] = __builtin_amdgcn_mfma_f32_16x16x32_f16(af[kk], bf, acc[ni], 0, 0, 0);
    }
  float ev[4][4], sm[4];
#pragma unroll
  for (int r = 0; r < 4; ++r) {
    int qrow = wave * 16 + q4 * 4 + r;
    float m = -1e30f;
#pragma unroll
    for (int ni = 0; ni < 4; ++ni) {
      int k = ni * 16 + lr;
      ev[ni][r] = acc[ni][r] * SCALE + bl[abs(qrow - k)];
      m = fmaxf(m, ev[ni][r]);
    }
    m = fmaxf(m, __shfl_xor(m, 1)); m = fmaxf(m, __shfl_xor(m, 2));
    m = fmaxf(m, __shfl_xor(m, 4)); m = fmaxf(m, __shfl_xor(m, 8));
    float s = 0.f;
#pragma unroll
    for (int ni = 0; ni < 4; ++ni) { ev[ni][r] = __expf(ev[ni][r] - m); s += ev[ni][r]; }
    s += __shfl_xor(s, 1); s += __shfl_xor(s, 2);
    s += __shfl_xor(s, 4); s += __shfl_xor(s, 8);
    sm[r] = 1.f / s;
  }
  _Float16* ab = attn + (((size_t)b * 64 + j) * 64) * 64;
#pragma unroll
  for (int r = 0; r < 4; ++r) {
    int qrow = wave * 16 + q4 * 4 + r;
#pragma unroll
    for (int ni = 0; ni < 4; ++ni)
      ab[qrow * 64 + ni * 16 + lr] = (_Float16)(ev[ni][r] * sm[r]);
  }
}

// ---- h-mix + relu + transposed write to ght ---- grid flat 8192
__global__ __launch_bounds__(256) void k_hmix(const _Float16* __restrict__ tT,
                                              const _Float16* __restrict__ attnH,
                                              _Float16* __restrict__ ght) {
  __shared__ __align__(16) _Float16 Ts[128 * 64];
  __shared__ __align__(16) _Float16 Ls[64 * 136];
  int id = blockIdx.x;
  int ct = id & 3, w = (id >> 2) & 63, b = id >> 8;
  int t = threadIdx.x, wid = t >> 6, lane = t & 63;
  int lr = lane & 15, q4 = lane >> 4;
  const _Float16* Tb = tT + ((size_t)b * 512 + ct * 128) * PIX + w * 64;
#pragma unroll
  for (int it = 0; it < 4; ++it) {
    int idx = it * 256 + t;
    int row = idx >> 3, c = idx & 7;
    int sc = c ^ (row & 7);
    gload_lds16(Tb + (size_t)row * PIX + sc * 8, &Ts[(it * 256 + wid * 64) * 8]);
  }
  const _Float16* Ab = attnH + ((size_t)b * 64 + w) * 4096;
  f16x8 bfr[4][2];
#pragma unroll
  for (int ni = 0; ni < 4; ++ni)
#pragma unroll
    for (int kk = 0; kk < 2; ++kk)
      bfr[ni][kk] = *(const f16x8*)&Ab[(ni * 16 + lr) * 64 + q4 * 8 + kk * 32];
  __syncthreads();
  f32x4 acc[2][4] = {};
#pragma unroll
  for (int mi = 0; mi < 2; ++mi) {
    int rr = wid * 32 + mi * 16 + lr;
#pragma unroll
    for (int kk = 0; kk < 2; ++kk) {
      f16x8 af = *(const f16x8*)&Ts[rr * 64 + (((q4 + 4 * kk) ^ (rr & 7)) << 3)];
#pragma unroll
      for (int ni = 0; ni < 4; ++ni)
        acc[mi][ni] = __builtin_amdgcn_mfma_f32_16x16x32_f16(af, bfr[ni][kk], acc[mi][ni], 0, 0, 0);
    }
  }
#pragma unroll
  for (int mi = 0; mi < 2; ++mi)
#pragma unroll
    for (int ni = 0; ni < 4; ++ni)
#pragma unroll
      for (int rr = 0; rr < 4; ++rr) {
        float v = acc[mi][ni][rr];
        Ls[(ni * 16 + lr) * 136 + wid * 32 + mi * 16 + q4 * 4 + rr] =
            (_Float16)(v > 0.f ? v : 0.f);
      }
  __syncthreads();
  _Float16* gb = ght + (size_t)b * PIX * 512 + ct * 128;
#pragma unroll
  for (int it = 0; it < 4; ++it) {
    int idx = it * 256 + t;
    int hp = idx >> 4, cc = (idx & 15) << 3;
    *(f16x8*)&gb[((size_t)hp * 64 + w) * 512 + cc] = *(const f16x8*)&Ls[hp * 136 + cc];
  }
}

// ---- 64x64 per-image fp16 transpose ---- grid (nb*nc)
__global__ __launch_bounds__(256) void k_t16(const _Float16* __restrict__ in,
                                             _Float16* __restrict__ out) {
  __shared__ _Float16 tile[64][65];
  int img = blockIdx.x;
  const _Float16* ip = in + (size_t)img * PIX;
  _Float16* op = out + (size_t)img * PIX;
  int t = threadIdx.x;
  int col = t & 63, r0 = t >> 6;
  for (int it = 0; it < 16; ++it) {
    int r = r0 + it * 4;
    tile[r][col] = ip[r * 64 + col];
  }
  __syncthreads();
  for (int it = 0; it < 16; ++it) {
    int r = r0 + it * 4;
    op[r * 64 + col] = tile[col][r];
  }
}

extern "C" void kernel_launch(void* const* d_in, const int* in_sizes, int n_in,
                              void* d_out, int out_size, void* d_ws, size_t ws_size,
                              hipStream_t stream) {
  const float* x      = (const float*)d_in[0];
  const float* qk_w   = (const float*)d_in[1];
  const float* qk_b   = (const float*)d_in[2];
  const float* dws_w  = (const float*)d_in[3];
  const float* dws_b  = (const float*)d_in[4];
  const float* vs_w   = (const float*)d_in[5];
  const float* vs_b   = (const float*)d_in[6];
  const float* proj_w = (const float*)d_in[7];
  const float* proj_b = (const float*)d_in[8];
  const float* bias_h = (const float*)d_in[9];
  const float* bias_w = (const float*)d_in[10];

  float* ws = (float*)d_ws;
  float* dout = (float*)d_out;

  // ws layout (float units):
  _Float16* xh    = (_Float16*)ws;                 // [0,33.5M fl); reused as ght
  _Float16* ght   = xh;
  float*    feat  = ws + 33554432;                 // fp32 q-half; reused as tT
  _Float16* tT    = (_Float16*)(ws + 33554432);
  _Float16* attnW = (_Float16*)(ws + 67108864);
  _Float16* attnH = (_Float16*)(ws + 71303168);
  _Float16* qkw_h  = (_Float16*)(ws + 75497472);
  _Float16* wbig_h = (_Float16*)(ws + 75563008);
  _Float16* pjw_h  = (_Float16*)(ws + 75694080);

  // d_out phase scratch:
  float*    qconv = dout;                          // [0,16.8M fl)
  _Float16* qh    = (_Float16*)(dout + 16777216);
  _Float16* kh    = (_Float16*)(dout + 25165824);
  _Float16* Vh    = (_Float16*)(dout + 33554432);  // t tiles (67.1M halves)

  k_cvt<<<dim3(512), 256, 0, stream>>>(qk_w, qkw_h, 131072);
  k_cvt<<<dim3(1024), 256, 0, stream>>>(proj_w, pjw_h, 262144);
  k_build_wbig<<<512, 256, 0, stream>>>(vs_w, wbig_h);
  k_xt<<<dim3(64, 8, 32), 256, 0, stream>>>(x, xh);
  // feat GEMM: q-half fp32 + kh fp16 fused (M=256)
  k_mg8<2><<<512, 512, 0, stream>>>(qkw_h, xh, qk_b, nullptr, feat, kh, 1);
  k_dwconv<<<dim3(128, 32), 256, 0, stream>>>(feat, dws_w, dws_b, qconv);
  k_qkt<<<dim3(64, 32), 256, 0, stream>>>(qconv, 128L * PIX, 0, qh);
  k_mattn<<<dim3(64, 32, 2), 256, 0, stream>>>(qh, kh, bias_w, bias_h, attnW, attnH);
  // V GEMM (triangular) + fused w-attn mix -> t
  k_mg8<1><<<1024, 512, 0, stream>>>(wbig_h, xh, vs_b, attnW, nullptr, Vh, 2);
  // tT = transpose(t)
  k_t16<<<32 * 512, 256, 0, stream>>>(Vh, tT);
  // ght = relu(attnH ⊙ tT), transposed to [p][512]
  k_hmix<<<8192, 256, 0, stream>>>(tT, attnH, ght);
  // out = proj_w @ g + proj_b (fp32)
  k_mg8<0><<<1024, 512, 0, stream>>>(pjw_h, ght, proj_b, nullptr, dout, nullptr, 2);
}